// Round 1
// baseline (90.130 us; speedup 1.0000x reference)
//
#include <hip/hip_runtime.h>
#include <hip/hip_bf16.h>
#include <hip/hip_fp16.h>

typedef unsigned int uint;
typedef unsigned short ushort;
typedef __attribute__((ext_vector_type(4))) float f32x4;
typedef __attribute__((ext_vector_type(8))) short bf16x8;

// async global->LDS, 16B per lane; LDS dest is wave-uniform-base + lane*16 (linear)
#define LDS16(gp, lp)                                                                    \
  __builtin_amdgcn_global_load_lds((const __attribute__((address_space(1))) uint*)(gp),  \
                                   (__attribute__((address_space(3))) uint*)(lp), 16, 0, 0)

__device__ __forceinline__ uint cvt_pk_bf16(float lo, float hi) {
  uint r;
  asm("v_cvt_pk_bf16_f32 %0, %1, %2" : "=v"(r) : "v"(lo), "v"(hi));
  return r;
}

// ---------------------------------------------------------------------------
// Kernel 1: split W (1024x511 f32, row-major) into transposed bf16 hi/lo
// W_hiT/W_loT layout: [512][1024] (n-major), col 511 zero-padded.
// hi = truncated bf16 (top 16 bits), lo = rne-bf16(w - hi_f32).
// ---------------------------------------------------------------------------
__global__ __launch_bounds__(256) void prep_w(const float* __restrict__ W,
                                              ushort* __restrict__ WhiT,
                                              ushort* __restrict__ WloT) {
  int tid = blockIdx.x * 256 + threadIdx.x;  // 0 .. 512*1024-1
  int n = tid >> 10, k = tid & 1023;
  float w = (n < 511) ? W[k * 511 + n] : 0.f;
  uint u = __float_as_uint(w);
  WhiT[n * 1024 + k] = (ushort)(u >> 16);
  float lo = w - __uint_as_float(u & 0xffff0000u);
  WloT[n * 1024 + k] = (ushort)(cvt_pk_bf16(lo, 0.f) & 0xffffu);
}

// ---------------------------------------------------------------------------
// Kernel 2: P = sigmoid(X @ W + b), stored f16 [16384][512] (col 511 junk).
// 128x128 tile, BK=32, 4 waves (2x2), 3-pass split-bf16 MFMA 16x16x32.
// A staged as f32 (global_load_lds, XOR-swizzled source), converted to
// hi/lo bf16 in-register. B staged from pre-split W_hiT/W_loT.
// ---------------------------------------------------------------------------
__global__ __launch_bounds__(256, 2) void gemm_sig(const float* __restrict__ X,
                                                   const ushort* __restrict__ WhiT,
                                                   const ushort* __restrict__ WloT,
                                                   const float* __restrict__ bvec,
                                                   __half* __restrict__ P) {
  __shared__ float  ldsA[128 * 32];   // 16 KB, row-major [r][k], 16B-chunk XOR swizz
  __shared__ ushort ldsBh[128 * 32];  // 8 KB, [c][k]
  __shared__ ushort ldsBl[128 * 32];  // 8 KB

  const int tid = threadIdx.x;
  const int lane = tid & 63;
  const int w = tid >> 6;
  const int wr = w >> 1, wc = w & 1;
  const int l16 = lane & 15;
  const int g = lane >> 4;

  const int mbase = (blockIdx.x >> 2) * 128;
  const int nbase = (blockIdx.x & 3) * 128;

  f32x4 acc[4][4];
#pragma unroll
  for (int i = 0; i < 4; ++i)
#pragma unroll
    for (int j = 0; j < 4; ++j) acc[i][j] = (f32x4)0.f;

  float bias[4];
#pragma unroll
  for (int ni = 0; ni < 4; ++ni) {
    int gc = nbase + wc * 64 + ni * 16 + l16;
    bias[ni] = (gc < 511) ? bvec[gc] : 0.f;
  }

  for (int kt = 0; kt < 32; ++kt) {
    const int k0 = kt * 32;
    // stage A: 1024 16B chunks; LDS pos (r, h') holds global chunk h = h'^(r&7)
#pragma unroll
    for (int i = 0; i < 4; ++i) {
      int l = tid + 256 * i;
      int r = l >> 3, hp = l & 7;
      int h = hp ^ (r & 7);
      LDS16(X + (size_t)(mbase + r) * 1024 + k0 + h * 4, ldsA + l * 4);
    }
    // stage B hi/lo: 512 chunks each; LDS pos (c, g') holds global chunk g = g'^((c>>1)&3)
#pragma unroll
    for (int i = 0; i < 2; ++i) {
      int l = tid + 256 * i;
      int c = l >> 2, gp = l & 3;
      int gs = gp ^ ((c >> 1) & 3);
      const int srcoff = (nbase + c) * 1024 + k0 + gs * 8;
      LDS16(WhiT + srcoff, ldsBh + l * 8);
      LDS16(WloT + srcoff, ldsBl + l * 8);
    }
    __syncthreads();

    bf16x8 bh[4], bl[4];
#pragma unroll
    for (int ni = 0; ni < 4; ++ni) {
      int c = wc * 64 + ni * 16 + l16;
      int off = c * 32 + ((g ^ ((c >> 1) & 3)) * 8);
      bh[ni] = *(const bf16x8*)&ldsBh[off];
      bl[ni] = *(const bf16x8*)&ldsBl[off];
    }
#pragma unroll
    for (int mi = 0; mi < 4; ++mi) {
      int r = wr * 64 + mi * 16 + l16;
      const f32x4 x0 = *(const f32x4*)&ldsA[r * 32 + (((2 * g) ^ (r & 7)) * 4)];
      const f32x4 x1 = *(const f32x4*)&ldsA[r * 32 + (((2 * g + 1) ^ (r & 7)) * 4)];
      float xs[8] = {x0[0], x0[1], x0[2], x0[3], x1[0], x1[1], x1[2], x1[3]};
      union { uint u[4]; bf16x8 v; } ahi, alo;
#pragma unroll
      for (int p = 0; p < 4; ++p) {
        uint u0 = __float_as_uint(xs[2 * p]);
        uint u1 = __float_as_uint(xs[2 * p + 1]);
        ahi.u[p] = __builtin_amdgcn_perm(u1, u0, 0x07060302);  // {hi16(x1),hi16(x0)}
        float lo0 = xs[2 * p] - __uint_as_float(u0 & 0xffff0000u);
        float lo1 = xs[2 * p + 1] - __uint_as_float(u1 & 0xffff0000u);
        alo.u[p] = cvt_pk_bf16(lo0, lo1);
      }
#pragma unroll
      for (int ni = 0; ni < 4; ++ni) {
        acc[mi][ni] = __builtin_amdgcn_mfma_f32_16x16x32_bf16(ahi.v, bh[ni], acc[mi][ni], 0, 0, 0);
        acc[mi][ni] = __builtin_amdgcn_mfma_f32_16x16x32_bf16(ahi.v, bl[ni], acc[mi][ni], 0, 0, 0);
        acc[mi][ni] = __builtin_amdgcn_mfma_f32_16x16x32_bf16(alo.v, bh[ni], acc[mi][ni], 0, 0, 0);
      }
    }
    __syncthreads();
  }

  // epilogue: bias + sigmoid, store f16
#pragma unroll
  for (int mi = 0; mi < 4; ++mi) {
#pragma unroll
    for (int ni = 0; ni < 4; ++ni) {
      int gc = nbase + wc * 64 + ni * 16 + l16;
#pragma unroll
      for (int q = 0; q < 4; ++q) {
        int gr = mbase + wr * 64 + mi * 16 + g * 4 + q;
        float z = acc[mi][ni][q] + bias[ni];
        float pv = 1.f / (1.f + __expf(-z));
        P[(size_t)gr * 512 + gc] = __float2half(pv);
      }
    }
  }
}

// ---------------------------------------------------------------------------
// Kernel 3: tree propagation + leaf matmul.
// 1 wave handles 16 rows. P rows staged into padded LDS (stride 520 halves,
// one global_load_lds issue per row so padding stays off the linear path).
// Lane (r=lane&15, g=lane>>4): for t=0..15 computes leaf probs for leaves
// [32t + 8g, 32t + 8g + 8) of row r, packs bf16 -> A-frag; leaf_logits held
// in registers as B-frags; out = 16 chained 16x16x32 MFMAs (K=512).
// ---------------------------------------------------------------------------
__global__ __launch_bounds__(256) void tree_out(const __half* __restrict__ P,
                                                const float* __restrict__ LL,
                                                float* __restrict__ out) {
  __shared__ __half plds[4 * 16 * 520];  // 65 KB
  const int tid = threadIdx.x;
  const int lane = tid & 63;
  const int wid = tid >> 6;
  const int r = lane & 15;
  const int g = lane >> 4;
  const int rbase = (blockIdx.x * 4 + wid) * 16;

  // stage: one issue per row (64 lanes x 16B = 1024B = full 512-half row)
#pragma unroll
  for (int i = 0; i < 16; ++i) {
    LDS16(P + (size_t)(rbase + i) * 512 + lane * 8, plds + (wid * 16 + i) * 520 + lane * 8);
  }

  // leaf_logits -> B-frags in registers (bf16), col = r (pad cols 10..15 = 0)
  union { uint u[4]; bf16x8 v; } bfr[16];
  const int col = r;
#pragma unroll
  for (int t = 0; t < 16; ++t) {
#pragma unroll
    for (int p = 0; p < 4; ++p) {
      int k0 = t * 32 + g * 8 + 2 * p;
      float e0 = (col < 10) ? LL[k0 * 10 + col] : 0.f;
      float e1 = (col < 10) ? LL[(k0 + 1) * 10 + col] : 0.f;
      bfr[t].u[p] = cvt_pk_bf16(e0, e1);
    }
  }

  asm volatile("s_waitcnt vmcnt(0)" ::: "memory");

  const __half* prow = &plds[(wid * 16 + r) * 520];
  f32x4 acc = (f32x4)0.f;
#pragma unroll
  for (int t = 0; t < 16; ++t) {
    const int L0 = g * 8 + 32 * t;  // chunk base leaf (multiple of 8)
    float pref = 1.f;
#pragma unroll
    for (int k = 0; k < 6; ++k) {
      int node = L0 >> (9 - k);
      int bit = (L0 >> (8 - k)) & 1;
      float pv = __half2float(prow[(1 << k) - 1 + node]);
      pref *= bit ? pv : (1.f - pv);
    }
    float p6 = __half2float(prow[63 + (L0 >> 3)]);
    float p7a = __half2float(prow[127 + (L0 >> 2)]);
    float p7b = __half2float(prow[128 + (L0 >> 2)]);
    float p80 = __half2float(prow[255 + (L0 >> 1)]);
    float p81 = __half2float(prow[256 + (L0 >> 1)]);
    float p82 = __half2float(prow[257 + (L0 >> 1)]);
    float p83 = __half2float(prow[258 + (L0 >> 1)]);
    float u1 = pref * p6, u0 = pref - u1;
    float v01 = u0 * p7a, v00 = u0 - v01;
    float v11 = u1 * p7b, v10 = u1 - v11;
    float pr1 = v00 * p80, pr0 = v00 - pr1;
    float pr3 = v01 * p81, pr2 = v01 - pr3;
    float pr5 = v10 * p82, pr4 = v10 - pr5;
    float pr7 = v11 * p83, pr6 = v11 - pr7;
    union { uint u[4]; bf16x8 v; } af;
    af.u[0] = cvt_pk_bf16(pr0, pr1);
    af.u[1] = cvt_pk_bf16(pr2, pr3);
    af.u[2] = cvt_pk_bf16(pr4, pr5);
    af.u[3] = cvt_pk_bf16(pr6, pr7);
    acc = __builtin_amdgcn_mfma_f32_16x16x32_bf16(af.v, bfr[t].v, acc, 0, 0, 0);
  }

  if (col < 10) {
#pragma unroll
    for (int q = 0; q < 4; ++q) out[(size_t)(rbase + g * 4 + q) * 10 + col] = acc[q];
  }
}

// ---------------------------------------------------------------------------
extern "C" void kernel_launch(void* const* d_in, const int* in_sizes, int n_in,
                              void* d_out, int out_size, void* d_ws, size_t ws_size,
                              hipStream_t stream) {
  const float* X = (const float*)d_in[0];
  const float* W = (const float*)d_in[1];
  const float* bv = (const float*)d_in[2];
  const float* LL = (const float*)d_in[3];
  float* out = (float*)d_out;

  __half* P = (__half*)d_ws;                                    // 16 MB
  ushort* WhiT = (ushort*)((char*)d_ws + (size_t)16384 * 512 * 2);  // 1 MB
  ushort* WloT = WhiT + 512 * 1024;                              // 1 MB

  prep_w<<<2048, 256, 0, stream>>>(W, WhiT, WloT);
  gemm_sig<<<512, 256, 0, stream>>>(X, WhiT, WloT, bv, P);
  tree_out<<<256, 256, 0, stream>>>(P, LL, out);
}

// Round 2
// 80.064 us; speedup vs baseline: 1.1257x; 1.1257x over previous
//
#include <hip/hip_runtime.h>
#include <hip/hip_bf16.h>
#include <hip/hip_fp16.h>

typedef unsigned int uint;
typedef unsigned short ushort;
typedef __attribute__((ext_vector_type(4))) float f32x4;
typedef __attribute__((ext_vector_type(8))) short bf16x8;

// async global->LDS, 16B per lane; LDS dest is wave-uniform-base + lane*16 (linear)
#define LDS16(gp, lp)                                                                    \
  __builtin_amdgcn_global_load_lds((const __attribute__((address_space(1))) uint*)(gp),  \
                                   (__attribute__((address_space(3))) uint*)(lp), 16, 0, 0)

__device__ __forceinline__ uint cvt_pk_bf16(float lo, float hi) {
  uint r;
  asm("v_cvt_pk_bf16_f32 %0, %1, %2" : "=v"(r) : "v"(lo), "v"(hi));
  return r;
}

// ---------------------------------------------------------------------------
// Kernel 1: split W (1024x511 f32, row-major) into transposed bf16 hi/lo.
// LDS 64x65 tile transpose so both read (along n) and write (along k) coalesce.
// W_hiT/W_loT layout: [512][1024] (n-major), col 511 zero-padded.
// ---------------------------------------------------------------------------
__global__ __launch_bounds__(256) void prep_w(const float* __restrict__ W,
                                              ushort* __restrict__ WhiT,
                                              ushort* __restrict__ WloT) {
  __shared__ float t[64][65];
  const int tid = threadIdx.x;
  const int k0 = (blockIdx.x >> 3) * 64;  // 16 k-tiles
  const int n0 = (blockIdx.x & 7) * 64;   // 8 n-tiles
#pragma unroll
  for (int i = 0; i < 16; ++i) {
    int idx = i * 256 + tid;
    int kk = idx >> 6, nn = idx & 63;
    int n = n0 + nn;
    t[kk][nn] = (n < 511) ? W[(size_t)(k0 + kk) * 511 + n] : 0.f;
  }
  __syncthreads();
#pragma unroll
  for (int i = 0; i < 16; ++i) {
    int idx = i * 256 + tid;
    int nn = idx >> 6, kk = idx & 63;
    float w = t[kk][nn];
    uint u = __float_as_uint(w);
    size_t o = (size_t)(n0 + nn) * 1024 + k0 + kk;
    WhiT[o] = (ushort)(u >> 16);
    float lo = w - __uint_as_float(u & 0xffff0000u);
    WloT[o] = (ushort)(cvt_pk_bf16(lo, 0.f) & 0xffffu);
  }
}

// ---------------------------------------------------------------------------
// Kernel 2: P = sigmoid(X @ W + b), stored f16 [16384][512] (col 511 junk).
// 128x128 tile, BK=32, 4 waves (2x2), 3-pass split-bf16 MFMA 16x16x32.
// Double-buffered LDS + prefetch: stage(kt+1) -> compute(kt) -> one barrier
// (its vmcnt(0) drain lands AFTER compute, hiding load latency).
// XCD-chunked swizzle: the 4 col-blocks of each X row-panel share an XCD L2.
// ---------------------------------------------------------------------------
__global__ __launch_bounds__(256, 2) void gemm_sig(const float* __restrict__ X,
                                                   const ushort* __restrict__ WhiT,
                                                   const ushort* __restrict__ WloT,
                                                   const float* __restrict__ bvec,
                                                   __half* __restrict__ P) {
  __shared__ float  ldsA[2][128 * 32];   // 2 x 16 KB, [r][k], 16B-chunk XOR swizz
  __shared__ ushort ldsBh[2][128 * 32];  // 2 x 8 KB, [c][k]
  __shared__ ushort ldsBl[2][128 * 32];  // 2 x 8 KB

  const int tid = threadIdx.x;
  const int lane = tid & 63;
  const int w = tid >> 6;
  const int wr = w >> 1, wc = w & 1;
  const int l16 = lane & 15;
  const int g = lane >> 4;

  // XCD-chunked swizzle (512 blocks, 8 XCDs, bijective)
  const int bid = blockIdx.x;
  const int swz = (bid & 7) * 64 + (bid >> 3);
  const int mbase = (swz >> 2) * 128;
  const int nbase = (swz & 3) * 128;

  f32x4 acc[4][4];
#pragma unroll
  for (int i = 0; i < 4; ++i)
#pragma unroll
    for (int j = 0; j < 4; ++j) acc[i][j] = (f32x4)0.f;

  float bias[4];
#pragma unroll
  for (int ni = 0; ni < 4; ++ni) {
    int gc = nbase + wc * 64 + ni * 16 + l16;
    bias[ni] = (gc < 511) ? bvec[gc] : 0.f;
  }

  auto stage = [&](int buf, int kt) {
    const int k0 = kt * 32;
    // A: 1024 16B chunks; LDS pos (r, h') holds global chunk h = h'^(r&7)
#pragma unroll
    for (int i = 0; i < 4; ++i) {
      int l = tid + 256 * i;
      int r = l >> 3, hp = l & 7;
      int h = hp ^ (r & 7);
      LDS16(X + (size_t)(mbase + r) * 1024 + k0 + h * 4, &ldsA[buf][l * 4]);
    }
    // B hi/lo: 512 chunks each; LDS pos (c, g') holds global chunk g = g'^((c>>1)&3)
#pragma unroll
    for (int i = 0; i < 2; ++i) {
      int l = tid + 256 * i;
      int c = l >> 2, gp = l & 3;
      int gs = gp ^ ((c >> 1) & 3);
      const int srcoff = (nbase + c) * 1024 + k0 + gs * 8;
      LDS16(WhiT + srcoff, &ldsBh[buf][l * 8]);
      LDS16(WloT + srcoff, &ldsBl[buf][l * 8]);
    }
  };

  auto compute = [&](int buf) {
    bf16x8 bh[4], bl[4];
#pragma unroll
    for (int ni = 0; ni < 4; ++ni) {
      int c = wc * 64 + ni * 16 + l16;
      int off = c * 32 + ((g ^ ((c >> 1) & 3)) * 8);
      bh[ni] = *(const bf16x8*)&ldsBh[buf][off];
      bl[ni] = *(const bf16x8*)&ldsBl[buf][off];
    }
#pragma unroll
    for (int mi = 0; mi < 4; ++mi) {
      int r = wr * 64 + mi * 16 + l16;
      const f32x4 x0 = *(const f32x4*)&ldsA[buf][r * 32 + (((2 * g) ^ (r & 7)) * 4)];
      const f32x4 x1 = *(const f32x4*)&ldsA[buf][r * 32 + (((2 * g + 1) ^ (r & 7)) * 4)];
      float xs[8] = {x0[0], x0[1], x0[2], x0[3], x1[0], x1[1], x1[2], x1[3]};
      union { uint u[4]; bf16x8 v; } ahi, alo;
#pragma unroll
      for (int p = 0; p < 4; ++p) {
        uint u0 = __float_as_uint(xs[2 * p]);
        uint u1 = __float_as_uint(xs[2 * p + 1]);
        ahi.u[p] = __builtin_amdgcn_perm(u1, u0, 0x07060302);  // {hi16(x1),hi16(x0)}
        float lo0 = xs[2 * p] - __uint_as_float(u0 & 0xffff0000u);
        float lo1 = xs[2 * p + 1] - __uint_as_float(u1 & 0xffff0000u);
        alo.u[p] = cvt_pk_bf16(lo0, lo1);
      }
#pragma unroll
      for (int ni = 0; ni < 4; ++ni) {
        acc[mi][ni] = __builtin_amdgcn_mfma_f32_16x16x32_bf16(ahi.v, bh[ni], acc[mi][ni], 0, 0, 0);
        acc[mi][ni] = __builtin_amdgcn_mfma_f32_16x16x32_bf16(ahi.v, bl[ni], acc[mi][ni], 0, 0, 0);
        acc[mi][ni] = __builtin_amdgcn_mfma_f32_16x16x32_bf16(alo.v, bh[ni], acc[mi][ni], 0, 0, 0);
      }
    }
  };

  stage(0, 0);
  __syncthreads();
  int cur = 0;
  for (int kt = 0; kt < 31; ++kt) {
    stage(cur ^ 1, kt + 1);   // prefetch next tile (async, stays in flight)
    compute(cur);             // MFMA on current tile hides load latency
    __syncthreads();          // single drain+barrier per tile, AFTER compute
    cur ^= 1;
  }
  compute(cur);  // last tile, no prefetch

  // epilogue: bias + sigmoid, store f16
#pragma unroll
  for (int mi = 0; mi < 4; ++mi) {
#pragma unroll
    for (int ni = 0; ni < 4; ++ni) {
      int gc = nbase + wc * 64 + ni * 16 + l16;
#pragma unroll
      for (int q = 0; q < 4; ++q) {
        int gr = mbase + wr * 64 + mi * 16 + g * 4 + q;
        float z = acc[mi][ni][q] + bias[ni];
        float pv = 1.f / (1.f + __expf(-z));
        P[(size_t)gr * 512 + gc] = __float2half(pv);
      }
    }
  }
}

// ---------------------------------------------------------------------------
// Kernel 3: tree propagation + leaf matmul.
// 1 block = 16 rows; 4 waves split the 16 t-chunks (4 each), partial f32x4
// accs reduced through LDS. Grid 1024 -> 4 blocks/CU (was 1) for latency hiding.
// ---------------------------------------------------------------------------
__global__ __launch_bounds__(256) void tree_out(const __half* __restrict__ P,
                                                const float* __restrict__ LL,
                                                float* __restrict__ out) {
  __shared__ __half plds[16 * 520];  // 16.25 KB, padded stride kills bank conflicts
  __shared__ f32x4 red[4][64];       // 4 KB
  const int tid = threadIdx.x;
  const int lane = tid & 63;
  const int wid = tid >> 6;
  const int r = lane & 15;
  const int g = lane >> 4;
  const int rbase = blockIdx.x * 16;

  // stage 4 rows per wave (64 lanes x 16B = full 512-half row per issue)
#pragma unroll
  for (int i = 0; i < 4; ++i) {
    int row = wid * 4 + i;
    LDS16(P + (size_t)(rbase + row) * 512 + lane * 8, plds + row * 520 + lane * 8);
  }

  // leaf_logits -> B-frags (bf16) for this wave's 4 t-chunks; col = r, pad 10..15 = 0
  union { uint u[4]; bf16x8 v; } bfr[4];
  const int col = r;
#pragma unroll
  for (int tt = 0; tt < 4; ++tt) {
    int t = wid * 4 + tt;
#pragma unroll
    for (int p = 0; p < 4; ++p) {
      int k0 = t * 32 + g * 8 + 2 * p;
      float e0 = (col < 10) ? LL[k0 * 10 + col] : 0.f;
      float e1 = (col < 10) ? LL[(k0 + 1) * 10 + col] : 0.f;
      bfr[tt].u[p] = cvt_pk_bf16(e0, e1);
    }
  }

  __syncthreads();  // drains vmcnt(0): all 16 rows staged

  const __half* prow = &plds[r * 520];
  f32x4 acc = (f32x4)0.f;
#pragma unroll
  for (int tt = 0; tt < 4; ++tt) {
    const int t = wid * 4 + tt;
    const int L0 = g * 8 + 32 * t;  // chunk base leaf (multiple of 8)
    float pref = 1.f;
#pragma unroll
    for (int k = 0; k < 6; ++k) {
      int node = L0 >> (9 - k);
      int bit = (L0 >> (8 - k)) & 1;
      float pv = __half2float(prow[(1 << k) - 1 + node]);
      pref *= bit ? pv : (1.f - pv);
    }
    float p6 = __half2float(prow[63 + (L0 >> 3)]);
    float p7a = __half2float(prow[127 + (L0 >> 2)]);
    float p7b = __half2float(prow[128 + (L0 >> 2)]);
    float p80 = __half2float(prow[255 + (L0 >> 1)]);
    float p81 = __half2float(prow[256 + (L0 >> 1)]);
    float p82 = __half2float(prow[257 + (L0 >> 1)]);
    float p83 = __half2float(prow[258 + (L0 >> 1)]);
    float u1 = pref * p6, u0 = pref - u1;
    float v01 = u0 * p7a, v00 = u0 - v01;
    float v11 = u1 * p7b, v10 = u1 - v11;
    float pr1 = v00 * p80, pr0 = v00 - pr1;
    float pr3 = v01 * p81, pr2 = v01 - pr3;
    float pr5 = v10 * p82, pr4 = v10 - pr5;
    float pr7 = v11 * p83, pr6 = v11 - pr7;
    union { uint u[4]; bf16x8 v; } af;
    af.u[0] = cvt_pk_bf16(pr0, pr1);
    af.u[1] = cvt_pk_bf16(pr2, pr3);
    af.u[2] = cvt_pk_bf16(pr4, pr5);
    af.u[3] = cvt_pk_bf16(pr6, pr7);
    acc = __builtin_amdgcn_mfma_f32_16x16x32_bf16(af.v, bfr[tt].v, acc, 0, 0, 0);
  }

  red[wid][lane] = acc;
  __syncthreads();
  if (wid == 0 && col < 10) {
    f32x4 a0 = red[0][lane], a1 = red[1][lane], a2 = red[2][lane], a3 = red[3][lane];
#pragma unroll
    for (int q = 0; q < 4; ++q)
      out[(size_t)(rbase + g * 4 + q) * 10 + col] = a0[q] + a1[q] + a2[q] + a3[q];
  }
}

// ---------------------------------------------------------------------------
extern "C" void kernel_launch(void* const* d_in, const int* in_sizes, int n_in,
                              void* d_out, int out_size, void* d_ws, size_t ws_size,
                              hipStream_t stream) {
  const float* X = (const float*)d_in[0];
  const float* W = (const float*)d_in[1];
  const float* bv = (const float*)d_in[2];
  const float* LL = (const float*)d_in[3];
  float* out = (float*)d_out;

  __half* P = (__half*)d_ws;                                        // 16 MB
  ushort* WhiT = (ushort*)((char*)d_ws + (size_t)16384 * 512 * 2);  // 1 MB
  ushort* WloT = WhiT + 512 * 1024;                                 // 1 MB

  prep_w<<<128, 256, 0, stream>>>(W, WhiT, WloT);
  gemm_sig<<<512, 256, 0, stream>>>(X, WhiT, WloT, bv, P);
  tree_out<<<1024, 256, 0, stream>>>(P, LL, out);
}

// Round 3
// 76.331 us; speedup vs baseline: 1.1808x; 1.0489x over previous
//
#include <hip/hip_runtime.h>
#include <hip/hip_bf16.h>
#include <hip/hip_fp16.h>

typedef unsigned int uint;
typedef unsigned short ushort;
typedef __attribute__((ext_vector_type(4))) float f32x4;
typedef __attribute__((ext_vector_type(8))) short bf16x8;

// async global->LDS, 16B per lane; LDS dest is wave-uniform-base + lane*16 (linear)
#define LDS16(gp, lp)                                                                    \
  __builtin_amdgcn_global_load_lds((const __attribute__((address_space(1))) uint*)(gp),  \
                                   (__attribute__((address_space(3))) uint*)(lp), 16, 0, 0)

__device__ __forceinline__ uint cvt_pk_bf16(float lo, float hi) {
  uint r;
  asm("v_cvt_pk_bf16_f32 %0, %1, %2" : "=v"(r) : "v"(lo), "v"(hi));
  return r;
}

// ---------------------------------------------------------------------------
// Kernel 1: split W (1024x511 f32, row-major) into transposed bf16 hi/lo.
// LDS 64x65 tile transpose so both read (along n) and write (along k) coalesce.
// ---------------------------------------------------------------------------
__global__ __launch_bounds__(256) void prep_w(const float* __restrict__ W,
                                              ushort* __restrict__ WhiT,
                                              ushort* __restrict__ WloT) {
  __shared__ float t[64][65];
  const int tid = threadIdx.x;
  const int k0 = (blockIdx.x >> 3) * 64;
  const int n0 = (blockIdx.x & 7) * 64;
#pragma unroll
  for (int i = 0; i < 16; ++i) {
    int idx = i * 256 + tid;
    int kk = idx >> 6, nn = idx & 63;
    int n = n0 + nn;
    t[kk][nn] = (n < 511) ? W[(size_t)(k0 + kk) * 511 + n] : 0.f;
  }
  __syncthreads();
#pragma unroll
  for (int i = 0; i < 16; ++i) {
    int idx = i * 256 + tid;
    int nn = idx >> 6, kk = idx & 63;
    float w = t[kk][nn];
    uint u = __float_as_uint(w);
    size_t o = (size_t)(n0 + nn) * 1024 + k0 + kk;
    WhiT[o] = (ushort)(u >> 16);
    float lo = w - __uint_as_float(u & 0xffff0000u);
    WloT[o] = (ushort)(cvt_pk_bf16(lo, 0.f) & 0xffffu);
  }
}

// ---------------------------------------------------------------------------
// Kernel 2: P = sigmoid(X @ W + b), f16 [16384][512] (col 511 junk).
// 128x128 tile, BK=32, 4 waves (2x2), 3-pass split-bf16 MFMA 16x16x32.
// Depth-2 pipeline with COUNTED vmcnt (T4): raw s_barrier, never drain to 0
// in the loop. 8 global_load_lds per thread per tile; vmcnt(8) at phase top
// means "current tile landed, next tile still in flight".
// ---------------------------------------------------------------------------
__global__ __launch_bounds__(256, 2) void gemm_sig(const float* __restrict__ X,
                                                   const ushort* __restrict__ WhiT,
                                                   const ushort* __restrict__ WloT,
                                                   const float* __restrict__ bvec,
                                                   __half* __restrict__ P) {
  __shared__ float  ldsA[2][128 * 32];   // 2 x 16 KB, [r][k], 16B-chunk XOR swizz
  __shared__ ushort ldsBh[2][128 * 32];  // 2 x 8 KB, [c][k]
  __shared__ ushort ldsBl[2][128 * 32];  // 2 x 8 KB

  const int tid = threadIdx.x;
  const int lane = tid & 63;
  const int w = tid >> 6;
  const int wr = w >> 1, wc = w & 1;
  const int l16 = lane & 15;
  const int g = lane >> 4;

  // XCD-chunked swizzle (512 blocks, 8 XCDs, bijective)
  const int bid = blockIdx.x;
  const int swz = (bid & 7) * 64 + (bid >> 3);
  const int mbase = (swz >> 2) * 128;
  const int nbase = (swz & 3) * 128;

  f32x4 acc[4][4];
#pragma unroll
  for (int i = 0; i < 4; ++i)
#pragma unroll
    for (int j = 0; j < 4; ++j) acc[i][j] = (f32x4)0.f;

  auto stage = [&](int buf, int kt) {
    const int k0 = kt * 32;
#pragma unroll
    for (int i = 0; i < 4; ++i) {
      int l = tid + 256 * i;
      int r = l >> 3, hp = l & 7;
      int h = hp ^ (r & 7);
      LDS16(X + (size_t)(mbase + r) * 1024 + k0 + h * 4, &ldsA[buf][l * 4]);
    }
#pragma unroll
    for (int i = 0; i < 2; ++i) {
      int l = tid + 256 * i;
      int c = l >> 2, gp = l & 3;
      int gs = gp ^ ((c >> 1) & 3);
      const int srcoff = (nbase + c) * 1024 + k0 + gs * 8;
      LDS16(WhiT + srcoff, &ldsBh[buf][l * 8]);
      LDS16(WloT + srcoff, &ldsBl[buf][l * 8]);
    }
  };

  auto compute = [&](int buf) {
    bf16x8 bh[4], bl[4];
#pragma unroll
    for (int ni = 0; ni < 4; ++ni) {
      int c = wc * 64 + ni * 16 + l16;
      int off = c * 32 + ((g ^ ((c >> 1) & 3)) * 8);
      bh[ni] = *(const bf16x8*)&ldsBh[buf][off];
      bl[ni] = *(const bf16x8*)&ldsBl[buf][off];
    }
#pragma unroll
    for (int mi = 0; mi < 4; ++mi) {
      int r = wr * 64 + mi * 16 + l16;
      const f32x4 x0 = *(const f32x4*)&ldsA[buf][r * 32 + (((2 * g) ^ (r & 7)) * 4)];
      const f32x4 x1 = *(const f32x4*)&ldsA[buf][r * 32 + (((2 * g + 1) ^ (r & 7)) * 4)];
      float xs[8] = {x0[0], x0[1], x0[2], x0[3], x1[0], x1[1], x1[2], x1[3]};
      union { uint u[4]; bf16x8 v; } ahi, alo;
#pragma unroll
      for (int p = 0; p < 4; ++p) {
        uint u0 = __float_as_uint(xs[2 * p]);
        uint u1 = __float_as_uint(xs[2 * p + 1]);
        ahi.u[p] = __builtin_amdgcn_perm(u1, u0, 0x07060302);  // {hi16(x1),hi16(x0)}
        float lo0 = xs[2 * p] - __uint_as_float(u0 & 0xffff0000u);
        float lo1 = xs[2 * p + 1] - __uint_as_float(u1 & 0xffff0000u);
        alo.u[p] = cvt_pk_bf16(lo0, lo1);
      }
#pragma unroll
      for (int ni = 0; ni < 4; ++ni) {
        acc[mi][ni] = __builtin_amdgcn_mfma_f32_16x16x32_bf16(ahi.v, bh[ni], acc[mi][ni], 0, 0, 0);
        acc[mi][ni] = __builtin_amdgcn_mfma_f32_16x16x32_bf16(ahi.v, bl[ni], acc[mi][ni], 0, 0, 0);
        acc[mi][ni] = __builtin_amdgcn_mfma_f32_16x16x32_bf16(alo.v, bh[ni], acc[mi][ni], 0, 0, 0);
      }
    }
  };

  stage(0, 0);
  stage(1, 1);

#pragma unroll 1
  for (int kt = 0; kt < 32; kt += 2) {
    // ---- even phase: buffer 0 holds tile kt ----
    asm volatile("s_waitcnt vmcnt(8)" ::: "memory");  // tile kt landed; kt+1 in flight
    __builtin_amdgcn_s_barrier();
    __builtin_amdgcn_sched_barrier(0);
    compute(0);
    __builtin_amdgcn_sched_barrier(0);
    __builtin_amdgcn_s_barrier();                     // all waves done reading buf 0
    if (kt + 2 < 32) stage(0, kt + 2);
    // ---- odd phase: buffer 1 holds tile kt+1 ----
    if (kt + 3 < 32) {
      asm volatile("s_waitcnt vmcnt(8)" ::: "memory");
    } else {
      asm volatile("s_waitcnt vmcnt(0)" ::: "memory");  // last tile: nothing else in flight
    }
    __builtin_amdgcn_s_barrier();
    __builtin_amdgcn_sched_barrier(0);
    compute(1);
    __builtin_amdgcn_sched_barrier(0);
    __builtin_amdgcn_s_barrier();
    if (kt + 3 < 32) stage(1, kt + 3);
  }

  // epilogue: bias + sigmoid, store f16 (bias loaded here: keeps loop vmcnt clean)
  float bias[4];
#pragma unroll
  for (int ni = 0; ni < 4; ++ni) {
    int gc = nbase + wc * 64 + ni * 16 + l16;
    bias[ni] = (gc < 511) ? bvec[gc] : 0.f;
  }
#pragma unroll
  for (int mi = 0; mi < 4; ++mi) {
#pragma unroll
    for (int ni = 0; ni < 4; ++ni) {
      int gc = nbase + wc * 64 + ni * 16 + l16;
#pragma unroll
      for (int q = 0; q < 4; ++q) {
        int gr = mbase + wr * 64 + mi * 16 + g * 4 + q;
        float z = acc[mi][ni][q] + bias[ni];
        float pv = 1.f / (1.f + __expf(-z));
        P[(size_t)gr * 512 + gc] = __float2half(pv);
      }
    }
  }
}

// ---------------------------------------------------------------------------
// Kernel 3: tree propagation + leaf matmul. 1 block = 16 rows; 4 waves split
// the 16 t-chunks, partial f32x4 accs reduced through LDS.
// ---------------------------------------------------------------------------
__global__ __launch_bounds__(256) void tree_out(const __half* __restrict__ P,
                                                const float* __restrict__ LL,
                                                float* __restrict__ out) {
  __shared__ __half plds[16 * 520];
  __shared__ f32x4 red[4][64];
  const int tid = threadIdx.x;
  const int lane = tid & 63;
  const int wid = tid >> 6;
  const int r = lane & 15;
  const int g = lane >> 4;
  const int rbase = blockIdx.x * 16;

#pragma unroll
  for (int i = 0; i < 4; ++i) {
    int row = wid * 4 + i;
    LDS16(P + (size_t)(rbase + row) * 512 + lane * 8, plds + row * 520 + lane * 8);
  }

  union { uint u[4]; bf16x8 v; } bfr[4];
  const int col = r;
#pragma unroll
  for (int tt = 0; tt < 4; ++tt) {
    int t = wid * 4 + tt;
#pragma unroll
    for (int p = 0; p < 4; ++p) {
      int k0 = t * 32 + g * 8 + 2 * p;
      float e0 = (col < 10) ? LL[k0 * 10 + col] : 0.f;
      float e1 = (col < 10) ? LL[(k0 + 1) * 10 + col] : 0.f;
      bfr[tt].u[p] = cvt_pk_bf16(e0, e1);
    }
  }

  __syncthreads();

  const __half* prow = &plds[r * 520];
  f32x4 acc = (f32x4)0.f;
#pragma unroll
  for (int tt = 0; tt < 4; ++tt) {
    const int t = wid * 4 + tt;
    const int L0 = g * 8 + 32 * t;
    float pref = 1.f;
#pragma unroll
    for (int k = 0; k < 6; ++k) {
      int node = L0 >> (9 - k);
      int bit = (L0 >> (8 - k)) & 1;
      float pv = __half2float(prow[(1 << k) - 1 + node]);
      pref *= bit ? pv : (1.f - pv);
    }
    float p6 = __half2float(prow[63 + (L0 >> 3)]);
    float p7a = __half2float(prow[127 + (L0 >> 2)]);
    float p7b = __half2float(prow[128 + (L0 >> 2)]);
    float p80 = __half2float(prow[255 + (L0 >> 1)]);
    float p81 = __half2float(prow[256 + (L0 >> 1)]);
    float p82 = __half2float(prow[257 + (L0 >> 1)]);
    float p83 = __half2float(prow[258 + (L0 >> 1)]);
    float u1 = pref * p6, u0 = pref - u1;
    float v01 = u0 * p7a, v00 = u0 - v01;
    float v11 = u1 * p7b, v10 = u1 - v11;
    float pr1 = v00 * p80, pr0 = v00 - pr1;
    float pr3 = v01 * p81, pr2 = v01 - pr3;
    float pr5 = v10 * p82, pr4 = v10 - pr5;
    float pr7 = v11 * p83, pr6 = v11 - pr7;
    union { uint u[4]; bf16x8 v; } af;
    af.u[0] = cvt_pk_bf16(pr0, pr1);
    af.u[1] = cvt_pk_bf16(pr2, pr3);
    af.u[2] = cvt_pk_bf16(pr4, pr5);
    af.u[3] = cvt_pk_bf16(pr6, pr7);
    acc = __builtin_amdgcn_mfma_f32_16x16x32_bf16(af.v, bfr[tt].v, acc, 0, 0, 0);
  }

  red[wid][lane] = acc;
  __syncthreads();
  if (wid == 0 && col < 10) {
    f32x4 a0 = red[0][lane], a1 = red[1][lane], a2 = red[2][lane], a3 = red[3][lane];
#pragma unroll
    for (int q = 0; q < 4; ++q)
      out[(size_t)(rbase + g * 4 + q) * 10 + col] = a0[q] + a1[q] + a2[q] + a3[q];
  }
}

// ---------------------------------------------------------------------------
extern "C" void kernel_launch(void* const* d_in, const int* in_sizes, int n_in,
                              void* d_out, int out_size, void* d_ws, size_t ws_size,
                              hipStream_t stream) {
  const float* X = (const float*)d_in[0];
  const float* W = (const float*)d_in[1];
  const float* bv = (const float*)d_in[2];
  const float* LL = (const float*)d_in[3];
  float* out = (float*)d_out;

  __half* P = (__half*)d_ws;                                        // 16 MB
  ushort* WhiT = (ushort*)((char*)d_ws + (size_t)16384 * 512 * 2);  // 1 MB
  ushort* WloT = WhiT + 512 * 1024;                                 // 1 MB

  prep_w<<<128, 256, 0, stream>>>(W, WhiT, WloT);
  gemm_sig<<<512, 256, 0, stream>>>(X, WhiT, WloT, bv, P);
  tree_out<<<1024, 256, 0, stream>>>(P, LL, out);
}

// Round 4
// 59.742 us; speedup vs baseline: 1.5086x; 1.2777x over previous
//
#include <hip/hip_runtime.h>
#include <hip/hip_bf16.h>
#include <hip/hip_fp16.h>

typedef unsigned int uint;
typedef unsigned short ushort;
typedef __attribute__((ext_vector_type(4))) float f32x4;
typedef __attribute__((ext_vector_type(8))) _Float16 f16x8;

// async global->LDS, 16B per lane; LDS dest is wave-uniform-base + lane*16 (linear)
#define LDS16(gp, lp)                                                                    \
  __builtin_amdgcn_global_load_lds((const __attribute__((address_space(1))) uint*)(gp),  \
                                   (__attribute__((address_space(3))) uint*)(lp), 16, 0, 0)

// ---------------------------------------------------------------------------
// Kernel 1: W (1024x511 f32, row-major) -> transposed f16 [512][1024],
// col 511 zero-padded. LDS 64x65 tile transpose keeps both sides coalesced.
// ---------------------------------------------------------------------------
__global__ __launch_bounds__(256) void prep_w(const float* __restrict__ W,
                                              _Float16* __restrict__ WT) {
  __shared__ float t[64][65];
  const int tid = threadIdx.x;
  const int k0 = (blockIdx.x >> 3) * 64;
  const int n0 = (blockIdx.x & 7) * 64;
#pragma unroll
  for (int i = 0; i < 16; ++i) {
    int idx = i * 256 + tid;
    int kk = idx >> 6, nn = idx & 63;
    int n = n0 + nn;
    t[kk][nn] = (n < 511) ? W[(size_t)(k0 + kk) * 511 + n] : 0.f;
  }
  __syncthreads();
#pragma unroll
  for (int i = 0; i < 16; ++i) {
    int idx = i * 256 + tid;
    int nn = idx >> 6, kk = idx & 63;
    WT[(size_t)(n0 + nn) * 1024 + k0 + kk] = (_Float16)t[kk][nn];
  }
}

// ---------------------------------------------------------------------------
// Kernel 2: P = sigmoid(X @ W + b), f16 [16384][512] (col 511 junk).
// 64x128 tile, BK=32, 4 waves (2x2, wave tile 32x64), single-pass f16 MFMA
// 16x16x32. Grid 1024 = 4 blocks/CU (4 waves/SIMD). Depth-2 pipeline with
// counted vmcnt(4) (T4): raw s_barrier, never drain to 0 in the loop.
// A staged f32 (XOR-swizzled source, linear LDS dest), converted f16 in-reg.
// ---------------------------------------------------------------------------
__global__ __launch_bounds__(256, 4) void gemm_sig(const float* __restrict__ X,
                                                   const _Float16* __restrict__ WT,
                                                   const float* __restrict__ bvec,
                                                   __half* __restrict__ P) {
  __shared__ float    ldsA[2][64 * 32];    // 2 x 8 KB, [r][k], 16B-chunk XOR swizz
  __shared__ _Float16 ldsB[2][128 * 32];   // 2 x 8 KB, [c][k], 16B-chunk XOR swizz

  const int tid = threadIdx.x;
  const int lane = tid & 63;
  const int w = tid >> 6;
  const int wr = w >> 1, wc = w & 1;
  const int l16 = lane & 15;
  const int g = lane >> 4;

  // XCD-chunked swizzle (1024 blocks, 8 XCDs, bijective)
  const int bid = blockIdx.x;
  const int swz = (bid & 7) * 128 + (bid >> 3);
  const int mbase = (swz >> 2) * 64;
  const int nbase = (swz & 3) * 128;

  f32x4 acc[2][4];
#pragma unroll
  for (int i = 0; i < 2; ++i)
#pragma unroll
    for (int j = 0; j < 4; ++j) acc[i][j] = (f32x4)0.f;

  auto stage = [&](int buf, int kt) {
    const int k0 = kt * 32;
    // A: 512 16B chunks (64 rows x 8); LDS pos (r, h') holds global chunk h'^(r&7)
#pragma unroll
    for (int i = 0; i < 2; ++i) {
      int l = tid + 256 * i;
      int r = l >> 3, hp = l & 7;
      int h = hp ^ (r & 7);
      LDS16(X + (size_t)(mbase + r) * 1024 + k0 + h * 4, &ldsA[buf][l * 4]);
    }
    // B: 512 16B chunks (128 cols x 4); LDS pos (c, g') holds global chunk g'^((c>>1)&3)
#pragma unroll
    for (int i = 0; i < 2; ++i) {
      int l = tid + 256 * i;
      int c = l >> 2, gp = l & 3;
      int gs = gp ^ ((c >> 1) & 3);
      LDS16(WT + (size_t)(nbase + c) * 1024 + k0 + gs * 8, &ldsB[buf][l * 8]);
    }
  };

  auto compute = [&](int buf) {
    f16x8 bfrag[4];
#pragma unroll
    for (int ni = 0; ni < 4; ++ni) {
      int c = wc * 64 + ni * 16 + l16;
      int off = c * 32 + ((g ^ ((c >> 1) & 3)) * 8);
      bfrag[ni] = *(const f16x8*)&ldsB[buf][off];
    }
#pragma unroll
    for (int mi = 0; mi < 2; ++mi) {
      int r = wr * 32 + mi * 16 + l16;
      const f32x4 x0 = *(const f32x4*)&ldsA[buf][r * 32 + (((2 * g) ^ (r & 7)) * 4)];
      const f32x4 x1 = *(const f32x4*)&ldsA[buf][r * 32 + (((2 * g + 1) ^ (r & 7)) * 4)];
      f16x8 a;
      a[0] = (_Float16)x0[0]; a[1] = (_Float16)x0[1];
      a[2] = (_Float16)x0[2]; a[3] = (_Float16)x0[3];
      a[4] = (_Float16)x1[0]; a[5] = (_Float16)x1[1];
      a[6] = (_Float16)x1[2]; a[7] = (_Float16)x1[3];
#pragma unroll
      for (int ni = 0; ni < 4; ++ni)
        acc[mi][ni] = __builtin_amdgcn_mfma_f32_16x16x32_f16(a, bfrag[ni], acc[mi][ni], 0, 0, 0);
    }
  };

  stage(0, 0);
  stage(1, 1);

#pragma unroll 1
  for (int kt = 0; kt < 32; kt += 2) {
    // ---- even phase: buffer 0 holds tile kt ----
    asm volatile("s_waitcnt vmcnt(4)" ::: "memory");  // tile kt landed; kt+1 in flight
    __builtin_amdgcn_s_barrier();
    __builtin_amdgcn_sched_barrier(0);
    compute(0);
    __builtin_amdgcn_sched_barrier(0);
    __builtin_amdgcn_s_barrier();                     // all waves done reading buf 0
    if (kt + 2 < 32) stage(0, kt + 2);
    // ---- odd phase: buffer 1 holds tile kt+1 ----
    if (kt + 3 < 32) {
      asm volatile("s_waitcnt vmcnt(4)" ::: "memory");
    } else {
      asm volatile("s_waitcnt vmcnt(0)" ::: "memory");  // tail: nothing else in flight
    }
    __builtin_amdgcn_s_barrier();
    __builtin_amdgcn_sched_barrier(0);
    compute(1);
    __builtin_amdgcn_sched_barrier(0);
    __builtin_amdgcn_s_barrier();
    if (kt + 3 < 32) stage(1, kt + 3);
  }

  // epilogue: bias + sigmoid, store f16
#pragma unroll
  for (int mi = 0; mi < 2; ++mi) {
#pragma unroll
    for (int ni = 0; ni < 4; ++ni) {
      int gc = nbase + wc * 64 + ni * 16 + l16;
      float bias = (gc < 511) ? bvec[gc] : 0.f;
#pragma unroll
      for (int q = 0; q < 4; ++q) {
        int gr = mbase + wr * 32 + mi * 16 + g * 4 + q;
        float z = acc[mi][ni][q] + bias;
        float pv = 1.f / (1.f + __expf(-z));
        P[(size_t)gr * 512 + gc] = __float2half(pv);
      }
    }
  }
}

// ---------------------------------------------------------------------------
// Kernel 3: tree propagation + leaf matmul (f16 MFMA for 4x better quant).
// 1 block = 16 rows; 4 waves split the 16 t-chunks, partials reduced in LDS.
// ---------------------------------------------------------------------------
__global__ __launch_bounds__(256) void tree_out(const __half* __restrict__ P,
                                                const float* __restrict__ LL,
                                                float* __restrict__ out) {
  __shared__ __half plds[16 * 520];
  __shared__ f32x4 red[4][64];
  const int tid = threadIdx.x;
  const int lane = tid & 63;
  const int wid = tid >> 6;
  const int r = lane & 15;
  const int g = lane >> 4;
  const int rbase = blockIdx.x * 16;

#pragma unroll
  for (int i = 0; i < 4; ++i) {
    int row = wid * 4 + i;
    LDS16(P + (size_t)(rbase + row) * 512 + lane * 8, plds + row * 520 + lane * 8);
  }

  f16x8 bfr[4];
  const int col = r;
#pragma unroll
  for (int tt = 0; tt < 4; ++tt) {
    int t = wid * 4 + tt;
#pragma unroll
    for (int p = 0; p < 8; ++p) {
      int k0 = t * 32 + g * 8 + p;
      bfr[tt][p] = (col < 10) ? (_Float16)LL[k0 * 10 + col] : (_Float16)0.f;
    }
  }

  __syncthreads();

  const __half* prow = &plds[r * 520];
  f32x4 acc = (f32x4)0.f;
#pragma unroll
  for (int tt = 0; tt < 4; ++tt) {
    const int t = wid * 4 + tt;
    const int L0 = g * 8 + 32 * t;
    float pref = 1.f;
#pragma unroll
    for (int k = 0; k < 6; ++k) {
      int node = L0 >> (9 - k);
      int bit = (L0 >> (8 - k)) & 1;
      float pv = __half2float(prow[(1 << k) - 1 + node]);
      pref *= bit ? pv : (1.f - pv);
    }
    float p6 = __half2float(prow[63 + (L0 >> 3)]);
    float p7a = __half2float(prow[127 + (L0 >> 2)]);
    float p7b = __half2float(prow[128 + (L0 >> 2)]);
    float p80 = __half2float(prow[255 + (L0 >> 1)]);
    float p81 = __half2float(prow[256 + (L0 >> 1)]);
    float p82 = __half2float(prow[257 + (L0 >> 1)]);
    float p83 = __half2float(prow[258 + (L0 >> 1)]);
    float u1 = pref * p6, u0 = pref - u1;
    float v01 = u0 * p7a, v00 = u0 - v01;
    float v11 = u1 * p7b, v10 = u1 - v11;
    float pr1 = v00 * p80, pr0 = v00 - pr1;
    float pr3 = v01 * p81, pr2 = v01 - pr3;
    float pr5 = v10 * p82, pr4 = v10 - pr5;
    float pr7 = v11 * p83, pr6 = v11 - pr7;
    f16x8 af;
    af[0] = (_Float16)pr0; af[1] = (_Float16)pr1;
    af[2] = (_Float16)pr2; af[3] = (_Float16)pr3;
    af[4] = (_Float16)pr4; af[5] = (_Float16)pr5;
    af[6] = (_Float16)pr6; af[7] = (_Float16)pr7;
    acc = __builtin_amdgcn_mfma_f32_16x16x32_f16(af, bfr[tt], acc, 0, 0, 0);
  }

  red[wid][lane] = acc;
  __syncthreads();
  if (wid == 0 && col < 10) {
    f32x4 a0 = red[0][lane], a1 = red[1][lane], a2 = red[2][lane], a3 = red[3][lane];
#pragma unroll
    for (int q = 0; q < 4; ++q)
      out[(size_t)(rbase + g * 4 + q) * 10 + col] = a0[q] + a1[q] + a2[q] + a3[q];
  }
}

// ---------------------------------------------------------------------------
extern "C" void kernel_launch(void* const* d_in, const int* in_sizes, int n_in,
                              void* d_out, int out_size, void* d_ws, size_t ws_size,
                              hipStream_t stream) {
  const float* X = (const float*)d_in[0];
  const float* W = (const float*)d_in[1];
  const float* bv = (const float*)d_in[2];
  const float* LL = (const float*)d_in[3];
  float* out = (float*)d_out;

  __half* P = (__half*)d_ws;                                           // 16 MB
  _Float16* WT = (_Float16*)((char*)d_ws + (size_t)16384 * 512 * 2);   // 1 MB

  prep_w<<<128, 256, 0, stream>>>(W, WT);
  gemm_sig<<<1024, 256, 0, stream>>>(X, WT, bv, P);
  tree_out<<<1024, 256, 0, stream>>>(P, LL, out);
}

// Round 5
// 56.965 us; speedup vs baseline: 1.5822x; 1.0487x over previous
//
#include <hip/hip_runtime.h>
#include <hip/hip_bf16.h>
#include <hip/hip_fp16.h>

typedef unsigned int uint;
typedef unsigned short ushort;
typedef __attribute__((ext_vector_type(4))) float f32x4;
typedef __attribute__((ext_vector_type(8))) _Float16 f16x8;

// async global->LDS, 16B per lane; LDS dest is wave-uniform-base + lane*16 (linear)
#define LDS16(gp, lp)                                                                    \
  __builtin_amdgcn_global_load_lds((const __attribute__((address_space(1))) uint*)(gp),  \
                                   (__attribute__((address_space(3))) uint*)(lp), 16, 0, 0)

// ---------------------------------------------------------------------------
// Kernel 1: W (1024x511 f32, row-major) -> transposed f16 [512][1024],
// col 511 zero-padded. LDS 64x65 tile transpose keeps both sides coalesced.
// ---------------------------------------------------------------------------
__global__ __launch_bounds__(256) void prep_w(const float* __restrict__ W,
                                              _Float16* __restrict__ WT) {
  __shared__ float t[64][65];
  const int tid = threadIdx.x;
  const int k0 = (blockIdx.x >> 3) * 64;
  const int n0 = (blockIdx.x & 7) * 64;
#pragma unroll
  for (int i = 0; i < 16; ++i) {
    int idx = i * 256 + tid;
    int kk = idx >> 6, nn = idx & 63;
    int n = n0 + nn;
    t[kk][nn] = (n < 511) ? W[(size_t)(k0 + kk) * 511 + n] : 0.f;
  }
  __syncthreads();
#pragma unroll
  for (int i = 0; i < 16; ++i) {
    int idx = i * 256 + tid;
    int nn = idx >> 6, kk = idx & 63;
    WT[(size_t)(n0 + nn) * 1024 + k0 + kk] = (_Float16)t[kk][nn];
  }
}

// ---------------------------------------------------------------------------
// Kernel 2: P = sigmoid(X @ W + b), f16 [16384][512] (col 511 junk).
// 128x128 tile, BK=32, 4 waves (2x2, wave tile 64x64), f16 MFMA 16x16x32.
// Grid 512 = 2 blocks/CU. DEPTH-3 pipeline, counted vmcnt: tiles kt..kt+2 in
// flight (6 loads/thread each); vmcnt(12) at phase top waits only the oldest,
// so each tile's loads get ~2 phases to land. Never drain to 0 in the loop.
// ---------------------------------------------------------------------------
__global__ __launch_bounds__(256, 2) void gemm_sig(const float* __restrict__ X,
                                                   const _Float16* __restrict__ WT,
                                                   const float* __restrict__ bvec,
                                                   __half* __restrict__ P) {
  __shared__ float    ldsA[3][128 * 32];   // 3 x 16 KB, [r][k], 16B-chunk XOR swizz
  __shared__ _Float16 ldsB[3][128 * 32];   // 3 x 8 KB,  [c][k], 16B-chunk XOR swizz

  const int tid = threadIdx.x;
  const int lane = tid & 63;
  const int w = tid >> 6;
  const int wr = w >> 1, wc = w & 1;
  const int l16 = lane & 15;
  const int g = lane >> 4;

  // XCD-chunked swizzle (512 blocks, 8 XCDs, bijective)
  const int bid = blockIdx.x;
  const int swz = (bid & 7) * 64 + (bid >> 3);
  const int mbase = (swz >> 2) * 128;
  const int nbase = (swz & 3) * 128;

  f32x4 acc[4][4];
#pragma unroll
  for (int i = 0; i < 4; ++i)
#pragma unroll
    for (int j = 0; j < 4; ++j) acc[i][j] = (f32x4)0.f;

  auto stage = [&](int buf, int kt) {
    const int k0 = kt * 32;
    // A: 1024 16B chunks (128 rows x 8); LDS pos (r, h') holds global chunk h'^(r&7)
#pragma unroll
    for (int i = 0; i < 4; ++i) {
      int l = tid + 256 * i;
      int r = l >> 3, hp = l & 7;
      int h = hp ^ (r & 7);
      LDS16(X + (size_t)(mbase + r) * 1024 + k0 + h * 4, &ldsA[buf][l * 4]);
    }
    // B: 512 16B chunks (128 cols x 4); LDS pos (c, g') holds global chunk g'^((c>>1)&3)
#pragma unroll
    for (int i = 0; i < 2; ++i) {
      int l = tid + 256 * i;
      int c = l >> 2, gp = l & 3;
      int gs = gp ^ ((c >> 1) & 3);
      LDS16(WT + (size_t)(nbase + c) * 1024 + k0 + gs * 8, &ldsB[buf][l * 8]);
    }
  };

  auto compute = [&](int buf) {
    f16x8 bfrag[4];
#pragma unroll
    for (int ni = 0; ni < 4; ++ni) {
      int c = wc * 64 + ni * 16 + l16;
      int off = c * 32 + ((g ^ ((c >> 1) & 3)) * 8);
      bfrag[ni] = *(const f16x8*)&ldsB[buf][off];
    }
#pragma unroll
    for (int mi = 0; mi < 4; ++mi) {
      int r = wr * 64 + mi * 16 + l16;
      const f32x4 x0 = *(const f32x4*)&ldsA[buf][r * 32 + (((2 * g) ^ (r & 7)) * 4)];
      const f32x4 x1 = *(const f32x4*)&ldsA[buf][r * 32 + (((2 * g + 1) ^ (r & 7)) * 4)];
      f16x8 a;
      a[0] = (_Float16)x0[0]; a[1] = (_Float16)x0[1];
      a[2] = (_Float16)x0[2]; a[3] = (_Float16)x0[3];
      a[4] = (_Float16)x1[0]; a[5] = (_Float16)x1[1];
      a[6] = (_Float16)x1[2]; a[7] = (_Float16)x1[3];
#pragma unroll
      for (int ni = 0; ni < 4; ++ni)
        acc[mi][ni] = __builtin_amdgcn_mfma_f32_16x16x32_f16(a, bfrag[ni], acc[mi][ni], 0, 0, 0);
    }
  };

  stage(0, 0);
  stage(1, 1);
  stage(2, 2);

  // PHASE(buf, kt, N): wait oldest tile landed (N = loads still allowed in
  // flight), barrier, compute, barrier, then refill this buffer with kt+3.
#define PHASE(BUF, KT, VM)                                   \
  asm volatile("s_waitcnt vmcnt(" #VM ")" ::: "memory");     \
  __builtin_amdgcn_s_barrier();                              \
  __builtin_amdgcn_sched_barrier(0);                         \
  compute(BUF);                                              \
  __builtin_amdgcn_sched_barrier(0);                         \
  __builtin_amdgcn_s_barrier();                              \
  if ((KT) + 3 < 32) stage(BUF, (KT) + 3);

#pragma unroll 1
  for (int i = 0; i < 10; ++i) {
    const int kt = 3 * i;
    PHASE(0, kt, 12)
    PHASE(1, kt + 1, 12)
    PHASE(2, kt + 2, 12)
  }
  // tail: kt=30 (only tile 31 in flight), kt=31 (nothing in flight)
  asm volatile("s_waitcnt vmcnt(6)" ::: "memory");
  __builtin_amdgcn_s_barrier();
  compute(0);
  __builtin_amdgcn_s_barrier();
  asm volatile("s_waitcnt vmcnt(0)" ::: "memory");
  __builtin_amdgcn_s_barrier();
  compute(1);
#undef PHASE

  // epilogue: bias + sigmoid, store f16
#pragma unroll
  for (int mi = 0; mi < 4; ++mi) {
#pragma unroll
    for (int ni = 0; ni < 4; ++ni) {
      int gc = nbase + wc * 64 + ni * 16 + l16;
      float bias = (gc < 511) ? bvec[gc] : 0.f;
#pragma unroll
      for (int q = 0; q < 4; ++q) {
        int gr = mbase + wr * 64 + mi * 16 + g * 4 + q;
        float z = acc[mi][ni][q] + bias;
        float pv = 1.f / (1.f + __expf(-z));
        P[(size_t)gr * 512 + gc] = __float2half(pv);
      }
    }
  }
}

// ---------------------------------------------------------------------------
// Kernel 3: tree propagation + leaf matmul (f16 MFMA).
// 1 block = 16 rows; 4 waves split the 16 t-chunks, partials reduced in LDS.
// ---------------------------------------------------------------------------
__global__ __launch_bounds__(256) void tree_out(const __half* __restrict__ P,
                                                const float* __restrict__ LL,
                                                float* __restrict__ out) {
  __shared__ __half plds[16 * 520];
  __shared__ f32x4 red[4][64];
  const int tid = threadIdx.x;
  const int lane = tid & 63;
  const int wid = tid >> 6;
  const int r = lane & 15;
  const int g = lane >> 4;
  const int rbase = blockIdx.x * 16;

#pragma unroll
  for (int i = 0; i < 4; ++i) {
    int row = wid * 4 + i;
    LDS16(P + (size_t)(rbase + row) * 512 + lane * 8, plds + row * 520 + lane * 8);
  }

  f16x8 bfr[4];
  const int col = r;
#pragma unroll
  for (int tt = 0; tt < 4; ++tt) {
    int t = wid * 4 + tt;
#pragma unroll
    for (int p = 0; p < 8; ++p) {
      int k0 = t * 32 + g * 8 + p;
      bfr[tt][p] = (col < 10) ? (_Float16)LL[k0 * 10 + col] : (_Float16)0.f;
    }
  }

  __syncthreads();

  const __half* prow = &plds[r * 520];
  f32x4 acc = (f32x4)0.f;
#pragma unroll
  for (int tt = 0; tt < 4; ++tt) {
    const int t = wid * 4 + tt;
    const int L0 = g * 8 + 32 * t;
    float pref = 1.f;
#pragma unroll
    for (int k = 0; k < 6; ++k) {
      int node = L0 >> (9 - k);
      int bit = (L0 >> (8 - k)) & 1;
      float pv = __half2float(prow[(1 << k) - 1 + node]);
      pref *= bit ? pv : (1.f - pv);
    }
    float p6 = __half2float(prow[63 + (L0 >> 3)]);
    float p7a = __half2float(prow[127 + (L0 >> 2)]);
    float p7b = __half2float(prow[128 + (L0 >> 2)]);
    float p80 = __half2float(prow[255 + (L0 >> 1)]);
    float p81 = __half2float(prow[256 + (L0 >> 1)]);
    float p82 = __half2float(prow[257 + (L0 >> 1)]);
    float p83 = __half2float(prow[258 + (L0 >> 1)]);
    float u1 = pref * p6, u0 = pref - u1;
    float v01 = u0 * p7a, v00 = u0 - v01;
    float v11 = u1 * p7b, v10 = u1 - v11;
    float pr1 = v00 * p80, pr0 = v00 - pr1;
    float pr3 = v01 * p81, pr2 = v01 - pr3;
    float pr5 = v10 * p82, pr4 = v10 - pr5;
    float pr7 = v11 * p83, pr6 = v11 - pr7;
    f16x8 af;
    af[0] = (_Float16)pr0; af[1] = (_Float16)pr1;
    af[2] = (_Float16)pr2; af[3] = (_Float16)pr3;
    af[4] = (_Float16)pr4; af[5] = (_Float16)pr5;
    af[6] = (_Float16)pr6; af[7] = (_Float16)pr7;
    acc = __builtin_amdgcn_mfma_f32_16x16x32_f16(af, bfr[tt], acc, 0, 0, 0);
  }

  red[wid][lane] = acc;
  __syncthreads();
  if (wid == 0 && col < 10) {
    f32x4 a0 = red[0][lane], a1 = red[1][lane], a2 = red[2][lane], a3 = red[3][lane];
#pragma unroll
    for (int q = 0; q < 4; ++q)
      out[(size_t)(rbase + g * 4 + q) * 10 + col] = a0[q] + a1[q] + a2[q] + a3[q];
  }
}

// ---------------------------------------------------------------------------
extern "C" void kernel_launch(void* const* d_in, const int* in_sizes, int n_in,
                              void* d_out, int out_size, void* d_ws, size_t ws_size,
                              hipStream_t stream) {
  const float* X = (const float*)d_in[0];
  const float* W = (const float*)d_in[1];
  const float* bv = (const float*)d_in[2];
  const float* LL = (const float*)d_in[3];
  float* out = (float*)d_out;

  __half* P = (__half*)d_ws;                                           // 16 MB
  _Float16* WT = (_Float16*)((char*)d_ws + (size_t)16384 * 512 * 2);   // 1 MB

  prep_w<<<128, 256, 0, stream>>>(W, WT);
  gemm_sig<<<512, 256, 0, stream>>>(X, WT, bv, P);
  tree_out<<<1024, 256, 0, stream>>>(P, LL, out);
}

// Round 7
// 53.520 us; speedup vs baseline: 1.6840x; 1.0644x over previous
//
#include <hip/hip_runtime.h>
#include <hip/hip_bf16.h>
#include <hip/hip_fp16.h>

typedef unsigned int uint;
typedef unsigned short ushort;
typedef __attribute__((ext_vector_type(4))) float f32x4;
typedef __attribute__((ext_vector_type(8))) _Float16 f16x8;

// async global->LDS, 16B per lane; LDS dest is wave-uniform-base + lane*16 (linear)
#define LDS16(gp, lp)                                                                    \
  __builtin_amdgcn_global_load_lds((const __attribute__((address_space(1))) uint*)(gp),  \
                                   (__attribute__((address_space(3))) uint*)(lp), 16, 0, 0)

// pack two f32 -> one u32 of two f16 (RTZ), via v_cvt_pkrtz_f16_f32
__device__ __forceinline__ uint pk_f16(float a, float b) {
  __fp16 __attribute__((ext_vector_type(2))) r = __builtin_amdgcn_cvt_pkrtz(a, b);
  union { decltype(r) v; uint u; } c;
  c.v = r;
  return c.u;
}

// ---------------------------------------------------------------------------
// Kernel 1: W (1024x511 f32, row-major) -> transposed f16 [512][1024],
// col 511 zero-padded. LDS 64x65 tile transpose keeps both sides coalesced.
// ---------------------------------------------------------------------------
__global__ __launch_bounds__(256) void prep_w(const float* __restrict__ W,
                                              _Float16* __restrict__ WT) {
  __shared__ float t[64][65];
  const int tid = threadIdx.x;
  const int k0 = (blockIdx.x >> 3) * 64;
  const int n0 = (blockIdx.x & 7) * 64;
#pragma unroll
  for (int i = 0; i < 16; ++i) {
    int idx = i * 256 + tid;
    int kk = idx >> 6, nn = idx & 63;
    int n = n0 + nn;
    t[kk][nn] = (n < 511) ? W[(size_t)(k0 + kk) * 511 + n] : 0.f;
  }
  __syncthreads();
#pragma unroll
  for (int i = 0; i < 16; ++i) {
    int idx = i * 256 + tid;
    int nn = idx >> 6, kk = idx & 63;
    WT[(size_t)(n0 + nn) * 1024 + k0 + kk] = (_Float16)t[kk][nn];
  }
}

// ---------------------------------------------------------------------------
// Kernel 2: P = sigmoid(X @ W + b), f16 [16384][512] (col 511 junk).
// 128x128 tile, BK=64, 16 phases, 512 threads (8 waves 2x4, wave tile 64x32).
// A: global_load -> regs (issued BEFORE compute, T14), cvt_pkrtz f16,
//    ds_write at next phase top. 2 LDS buffers [128][64] f16, XOR-swizzled.
// B: global_load_lds (pre-swizzled source), issued after end barrier, 2 bufs.
// Counted vmcnt(2): one tile ahead in flight; vmcnt(0) only at the last tile.
// ---------------------------------------------------------------------------
__global__ __launch_bounds__(512, 4) void gemm_sig(const float* __restrict__ X,
                                                   const _Float16* __restrict__ WT,
                                                   const float* __restrict__ bvec,
                                                   __half* __restrict__ P) {
  __shared__ _Float16 ldsA[2][128 * 64];  // 2 x 16 KB
  __shared__ _Float16 ldsB[2][128 * 64];  // 2 x 16 KB

  const int tid = threadIdx.x;
  const int lane = tid & 63;
  const int w = tid >> 6;
  const int wr = w >> 2, wc = w & 3;   // 8 waves as 2(M) x 4(N)
  const int l16 = lane & 15;
  const int g = lane >> 4;

  // XCD-chunked swizzle (512 blocks, 8 XCDs, bijective)
  const int bid = blockIdx.x;
  const int swz = (bid & 7) * 64 + (bid >> 3);
  const int mbase = (swz >> 2) * 128;
  const int nbase = (swz & 3) * 128;

  // A-staging mapping: 4 threads per row, 16 contiguous floats each
  const int arow = tid >> 2;  // 0..127
  const int aq = tid & 3;     // quarter within the 64-float row
  const float* aSrcBase = X + (size_t)(mbase + arow) * 1024 + aq * 16;
  const int ah0 = ((aq * 2) ^ (arow & 7)) * 8;      // swizzled 16B-chunk offsets
  const int ah1 = ((aq * 2 + 1) ^ (arow & 7)) * 8;

  f32x4 acc[4][2];
#pragma unroll
  for (int i = 0; i < 4; ++i)
#pragma unroll
    for (int j = 0; j < 2; ++j) acc[i][j] = (f32x4)0.f;

  f32x4 aReg[4];

  auto issueA = [&](int kt) {  // global f32 -> regs (4 x dwordx4)
    const float* s = aSrcBase + kt * 64;
    aReg[0] = *(const f32x4*)(s);
    aReg[1] = *(const f32x4*)(s + 4);
    aReg[2] = *(const f32x4*)(s + 8);
    aReg[3] = *(const f32x4*)(s + 12);
  };

  auto writeA = [&](int buf) {  // cvt f16 + 2 x ds_write_b128 (swizzled)
    union { uint u[8]; f16x8 w2[2]; } c;
#pragma unroll
    for (int j = 0; j < 4; ++j) {
      c.u[2 * j]     = pk_f16(aReg[j][0], aReg[j][1]);
      c.u[2 * j + 1] = pk_f16(aReg[j][2], aReg[j][3]);
    }
    *(f16x8*)&ldsA[buf][arow * 64 + ah0] = c.w2[0];
    *(f16x8*)&ldsA[buf][arow * 64 + ah1] = c.w2[1];
  };

  auto issueB = [&](int buf, int kt) {  // 2 x global_load_lds, pre-swizzled src
#pragma unroll
    for (int i = 0; i < 2; ++i) {
      int l = tid + 512 * i;
      int c = l >> 3, gp = l & 7;
      int gs = gp ^ (c & 7);
      LDS16(WT + (size_t)(nbase + c) * 1024 + kt * 64 + gs * 8, &ldsB[buf][l * 8]);
    }
  };

  auto compute = [&](int buf) {
#pragma unroll
    for (int kk = 0; kk < 2; ++kk) {
      f16x8 b[2], a[4];
#pragma unroll
      for (int ni = 0; ni < 2; ++ni) {
        int c = wc * 32 + ni * 16 + l16;
        b[ni] = *(const f16x8*)&ldsB[buf][c * 64 + (((kk * 4 + g) ^ (c & 7)) * 8)];
      }
#pragma unroll
      for (int mi = 0; mi < 4; ++mi) {
        int r = wr * 64 + mi * 16 + l16;
        a[mi] = *(const f16x8*)&ldsA[buf][r * 64 + (((kk * 4 + g) ^ (r & 7)) * 8)];
      }
#pragma unroll
      for (int mi = 0; mi < 4; ++mi)
#pragma unroll
        for (int ni = 0; ni < 2; ++ni)
          acc[mi][ni] = __builtin_amdgcn_mfma_f32_16x16x32_f16(a[mi], b[ni], acc[mi][ni], 0, 0, 0);
    }
  };

  // prologue: B(0), A(0), B(1) -> 8 VMEM in flight; vmcnt(2) leaves B(1) flying
  issueB(0, 0);
  issueA(0);
  issueB(1, 1);

#pragma unroll
  for (int t = 0; t < 16; ++t) {
    const int buf = t & 1;
    if (t < 15) {
      asm volatile("s_waitcnt vmcnt(2)" ::: "memory");  // A(t)+B(t) landed; B(t+1) flying
    } else {
      asm volatile("s_waitcnt vmcnt(0)" ::: "memory");  // last tile: drain
    }
    __builtin_amdgcn_sched_barrier(0);
    writeA(buf);                                         // regs(t) -> ldsA[buf]
    asm volatile("s_waitcnt lgkmcnt(0)" ::: "memory");   // my ds_writes visible
    __builtin_amdgcn_sched_barrier(0);
    __builtin_amdgcn_s_barrier();                        // all A writes + B loads ready
    __builtin_amdgcn_sched_barrier(0);
    if (t + 1 < 16) issueA(t + 1);                       // A(t+1) flies under compute
    __builtin_amdgcn_sched_barrier(0);
    __builtin_amdgcn_s_setprio(1);
    compute(buf);
    __builtin_amdgcn_s_setprio(0);
    __builtin_amdgcn_sched_barrier(0);
    __builtin_amdgcn_s_barrier();                        // all waves done reading buf
    if (t + 2 < 16) issueB(buf, t + 2);                  // refill this buf for t+2
  }

  // epilogue: bias + sigmoid, store f16
#pragma unroll
  for (int mi = 0; mi < 4; ++mi) {
#pragma unroll
    for (int ni = 0; ni < 2; ++ni) {
      int gc = nbase + wc * 32 + ni * 16 + l16;
      float bias = (gc < 511) ? bvec[gc] : 0.f;
#pragma unroll
      for (int q = 0; q < 4; ++q) {
        int gr = mbase + wr * 64 + mi * 16 + g * 4 + q;
        float z = acc[mi][ni][q] + bias;
        float pv = 1.f / (1.f + __expf(-z));
        P[(size_t)gr * 512 + gc] = __float2half(pv);
      }
    }
  }
}

// ---------------------------------------------------------------------------
// Kernel 3: tree propagation + leaf matmul (f16 MFMA).
// 1 block = 16 rows; 4 waves split the 16 t-chunks, partials reduced in LDS.
// ---------------------------------------------------------------------------
__global__ __launch_bounds__(256) void tree_out(const __half* __restrict__ P,
                                                const float* __restrict__ LL,
                                                float* __restrict__ out) {
  __shared__ __half plds[16 * 520];
  __shared__ f32x4 red[4][64];
  const int tid = threadIdx.x;
  const int lane = tid & 63;
  const int wid = tid >> 6;
  const int r = lane & 15;
  const int g = lane >> 4;
  const int rbase = blockIdx.x * 16;

#pragma unroll
  for (int i = 0; i < 4; ++i) {
    int row = wid * 4 + i;
    LDS16(P + (size_t)(rbase + row) * 512 + lane * 8, plds + row * 520 + lane * 8);
  }

  f16x8 bfr[4];
  const int col = r;
#pragma unroll
  for (int tt = 0; tt < 4; ++tt) {
    int t = wid * 4 + tt;
#pragma unroll
    for (int p = 0; p < 8; ++p) {
      int k0 = t * 32 + g * 8 + p;
      bfr[tt][p] = (col < 10) ? (_Float16)LL[k0 * 10 + col] : (_Float16)0.f;
    }
  }

  __syncthreads();

  const __half* prow = &plds[r * 520];
  f32x4 acc = (f32x4)0.f;
#pragma unroll
  for (int tt = 0; tt < 4; ++tt) {
    const int t = wid * 4 + tt;
    const int L0 = g * 8 + 32 * t;
    float pref = 1.f;
#pragma unroll
    for (int k = 0; k < 6; ++k) {
      int node = L0 >> (9 - k);
      int bit = (L0 >> (8 - k)) & 1;
      float pv = __half2float(prow[(1 << k) - 1 + node]);
      pref *= bit ? pv : (1.f - pv);
    }
    float p6 = __half2float(prow[63 + (L0 >> 3)]);
    float p7a = __half2float(prow[127 + (L0 >> 2)]);
    float p7b = __half2float(prow[128 + (L0 >> 2)]);
    float p80 = __half2float(prow[255 + (L0 >> 1)]);
    float p81 = __half2float(prow[256 + (L0 >> 1)]);
    float p82 = __half2float(prow[257 + (L0 >> 1)]);
    float p83 = __half2float(prow[258 + (L0 >> 1)]);
    float u1 = pref * p6, u0 = pref - u1;
    float v01 = u0 * p7a, v00 = u0 - v01;
    float v11 = u1 * p7b, v10 = u1 - v11;
    float pr1 = v00 * p80, pr0 = v00 - pr1;
    float pr3 = v01 * p81, pr2 = v01 - pr3;
    float pr5 = v10 * p82, pr4 = v10 - pr5;
    float pr7 = v11 * p83, pr6 = v11 - pr7;
    f16x8 af;
    af[0] = (_Float16)pr0; af[1] = (_Float16)pr1;
    af[2] = (_Float16)pr2; af[3] = (_Float16)pr3;
    af[4] = (_Float16)pr4; af[5] = (_Float16)pr5;
    af[6] = (_Float16)pr6; af[7] = (_Float16)pr7;
    acc = __builtin_amdgcn_mfma_f32_16x16x32_f16(af, bfr[tt], acc, 0, 0, 0);
  }

  red[wid][lane] = acc;
  __syncthreads();
  if (wid == 0 && col < 10) {
    f32x4 a0 = red[0][lane], a1 = red[1][lane], a2 = red[2][lane], a3 = red[3][lane];
#pragma unroll
    for (int q = 0; q < 4; ++q)
      out[(size_t)(rbase + g * 4 + q) * 10 + col] = a0[q] + a1[q] + a2[q] + a3[q];
  }
}

// ---------------------------------------------------------------------------
extern "C" void kernel_launch(void* const* d_in, const int* in_sizes, int n_in,
                              void* d_out, int out_size, void* d_ws, size_t ws_size,
                              hipStream_t stream) {
  const float* X = (const float*)d_in[0];
  const float* W = (const float*)d_in[1];
  const float* bv = (const float*)d_in[2];
  const float* LL = (const float*)d_in[3];
  float* out = (float*)d_out;

  __half* P = (__half*)d_ws;                                           // 16 MB
  _Float16* WT = (_Float16*)((char*)d_ws + (size_t)16384 * 512 * 2);   // 1 MB

  prep_w<<<128, 256, 0, stream>>>(W, WT);
  gemm_sig<<<512, 512, 0, stream>>>(X, WT, bv, P);
  tree_out<<<1024, 256, 0, stream>>>(P, LL, out);
}

// Round 8
// 52.196 us; speedup vs baseline: 1.7267x; 1.0254x over previous
//
#include <hip/hip_runtime.h>
#include <hip/hip_bf16.h>
#include <hip/hip_fp16.h>

typedef unsigned int uint;
typedef unsigned short ushort;
typedef __attribute__((ext_vector_type(4))) float f32x4;
typedef __attribute__((ext_vector_type(8))) _Float16 f16x8;

// async global->LDS, 16B per lane; LDS dest is wave-uniform-base + lane*16 (linear)
#define LDS16(gp, lp)                                                                    \
  __builtin_amdgcn_global_load_lds((const __attribute__((address_space(1))) uint*)(gp),  \
                                   (__attribute__((address_space(3))) uint*)(lp), 16, 0, 0)

// pack two f32 -> one u32 of two f16 (RTZ), via v_cvt_pkrtz_f16_f32
__device__ __forceinline__ uint pk_f16(float a, float b) {
  __fp16 __attribute__((ext_vector_type(2))) r = __builtin_amdgcn_cvt_pkrtz(a, b);
  union { decltype(r) v; uint u; } c;
  c.v = r;
  return c.u;
}

// ---------------------------------------------------------------------------
// Kernel 1: W (1024x511 f32, row-major) -> transposed f16 [512][1024],
// col 511 zero-padded. LDS 64x65 tile transpose keeps both sides coalesced.
// ---------------------------------------------------------------------------
__global__ __launch_bounds__(256) void prep_w(const float* __restrict__ W,
                                              _Float16* __restrict__ WT) {
  __shared__ float t[64][65];
  const int tid = threadIdx.x;
  const int k0 = (blockIdx.x >> 3) * 64;
  const int n0 = (blockIdx.x & 7) * 64;
#pragma unroll
  for (int i = 0; i < 16; ++i) {
    int idx = i * 256 + tid;
    int kk = idx >> 6, nn = idx & 63;
    int n = n0 + nn;
    t[kk][nn] = (n < 511) ? W[(size_t)(k0 + kk) * 511 + n] : 0.f;
  }
  __syncthreads();
#pragma unroll
  for (int i = 0; i < 16; ++i) {
    int idx = i * 256 + tid;
    int nn = idx >> 6, kk = idx & 63;
    WT[(size_t)(n0 + nn) * 1024 + k0 + kk] = (_Float16)t[kk][nn];
  }
}

// ---------------------------------------------------------------------------
// Kernel 2: P = sigmoid(X @ W + b), f16 [16384][512] (col 511 junk).
// REUSE-FIRST tiling: 64 rows x FULL 512 cols per block -> X read exactly
// once; B (1MB f16) is L2-resident and shared by all blocks of an XCD.
// Grid 256 (1 block/CU), 1024 threads (16 waves 2x8, wave tile 32x64), BK=64.
// A: threads 0..511 reg-stage f32 -> cvt f16 -> swizzled ds_write_b128.
// B: 4x global_load_lds per thread (pre-swizzled source), double-buffered.
// Counted vmcnt(4) steady state (uniform across both thread halves).
// ---------------------------------------------------------------------------
__global__ __launch_bounds__(1024, 4) void gemm_sig(const float* __restrict__ X,
                                                    const _Float16* __restrict__ WT,
                                                    const float* __restrict__ bvec,
                                                    __half* __restrict__ P) {
  __shared__ _Float16 ldsA[2][64 * 64];    // 2 x 8 KB
  __shared__ _Float16 ldsB[2][512 * 64];   // 2 x 64 KB

  const int tid = threadIdx.x;            // 0..1023
  const int lane = tid & 63;
  const int w = tid >> 6;                 // 0..15
  const int wr = w >> 3, wc = w & 7;      // 2(M) x 8(N)
  const int l16 = lane & 15;
  const int g = lane >> 4;
  const int rbase = blockIdx.x * 64;

  // A staging (threads 0..511): row = tid>>3, 8 consecutive f32 per thread
  const bool doA = (tid < 512);
  const int arow = tid >> 3;
  const int aseg = tid & 7;
  const float* aSrc = X + (size_t)(rbase + arow) * 1024 + aseg * 8;
  const int awOff = arow * 64 + (aseg ^ (arow & 7)) * 8;  // swizzled 16B slot

  f32x4 acc[2][4];
#pragma unroll
  for (int i = 0; i < 2; ++i)
#pragma unroll
    for (int j = 0; j < 4; ++j) acc[i][j] = (f32x4)0.f;

  f32x4 aReg[2];

  auto issueA = [&](int kt) {  // global f32 -> regs (2 x dwordx4)
    if (doA) {
      const float* s = aSrc + kt * 64;
      aReg[0] = *(const f32x4*)(s);
      aReg[1] = *(const f32x4*)(s + 4);
    }
  };

  auto writeA = [&](int buf) {  // cvt f16 + 1 x ds_write_b128 (swizzled)
    if (doA) {
      union { uint u[4]; f16x8 v; } c;
      c.u[0] = pk_f16(aReg[0][0], aReg[0][1]);
      c.u[1] = pk_f16(aReg[0][2], aReg[0][3]);
      c.u[2] = pk_f16(aReg[1][0], aReg[1][1]);
      c.u[3] = pk_f16(aReg[1][2], aReg[1][3]);
      *(f16x8*)&ldsA[buf][awOff] = c.v;
    }
  };

  auto issueB = [&](int buf, int kt) {  // 4 x global_load_lds, pre-swizzled src
#pragma unroll
    for (int i = 0; i < 4; ++i) {
      int l = tid + 1024 * i;
      int c = l >> 3, gp = l & 7;
      int gs = gp ^ (c & 7);
      LDS16(WT + (size_t)c * 1024 + kt * 64 + gs * 8, &ldsB[buf][l * 8]);
    }
  };

  auto compute = [&](int buf) {
#pragma unroll
    for (int kk = 0; kk < 2; ++kk) {
      f16x8 b[4], a[2];
#pragma unroll
      for (int ni = 0; ni < 4; ++ni) {
        int c = wc * 64 + ni * 16 + l16;
        b[ni] = *(const f16x8*)&ldsB[buf][c * 64 + (((kk * 4 + g) ^ (c & 7)) * 8)];
      }
#pragma unroll
      for (int mi = 0; mi < 2; ++mi) {
        int r = wr * 32 + mi * 16 + l16;
        a[mi] = *(const f16x8*)&ldsA[buf][r * 64 + (((kk * 4 + g) ^ (r & 7)) * 8)];
      }
#pragma unroll
      for (int mi = 0; mi < 2; ++mi)
#pragma unroll
        for (int ni = 0; ni < 4; ++ni)
          acc[mi][ni] = __builtin_amdgcn_mfma_f32_16x16x32_f16(a[mi], b[ni], acc[mi][ni], 0, 0, 0);
    }
  };

  // prologue: B(0)[4], A(0)[2], B(1)[4] in flight
  issueB(0, 0);
  issueA(0);
  issueB(1, 1);

#pragma unroll
  for (int t = 0; t < 16; ++t) {
    const int buf = t & 1;
    if (t < 15) {
      asm volatile("s_waitcnt vmcnt(4)" ::: "memory");  // B(t)+A(t) landed; B(t+1) flying
    } else {
      asm volatile("s_waitcnt vmcnt(0)" ::: "memory");  // last tile: drain
    }
    __builtin_amdgcn_sched_barrier(0);
    writeA(buf);                                         // regs(t) -> ldsA[buf]
    asm volatile("s_waitcnt lgkmcnt(0)" ::: "memory");   // my ds_write visible
    __builtin_amdgcn_sched_barrier(0);
    __builtin_amdgcn_s_barrier();                        // A writes + B loads ready
    __builtin_amdgcn_sched_barrier(0);
    if (t + 1 < 16) issueA(t + 1);                       // A(t+1) flies under compute
    __builtin_amdgcn_sched_barrier(0);
    __builtin_amdgcn_s_setprio(1);
    compute(buf);
    __builtin_amdgcn_s_setprio(0);
    __builtin_amdgcn_sched_barrier(0);
    __builtin_amdgcn_s_barrier();                        // all waves done reading buf
    if (t + 2 < 16) issueB(buf, t + 2);                  // refill this buf for t+2
  }

  // epilogue: bias + sigmoid, store f16
#pragma unroll
  for (int mi = 0; mi < 2; ++mi) {
#pragma unroll
    for (int ni = 0; ni < 4; ++ni) {
      int gc = wc * 64 + ni * 16 + l16;
      float bias = (gc < 511) ? bvec[gc] : 0.f;
#pragma unroll
      for (int q = 0; q < 4; ++q) {
        int gr = rbase + wr * 32 + mi * 16 + g * 4 + q;
        float z = acc[mi][ni][q] + bias;
        float pv = 1.f / (1.f + __expf(-z));
        P[(size_t)gr * 512 + gc] = __float2half(pv);
      }
    }
  }
}

// ---------------------------------------------------------------------------
// Kernel 3: tree propagation + leaf matmul (f16 MFMA).
// 1 block = 16 rows; 4 waves split the 16 t-chunks, partials reduced in LDS.
// ---------------------------------------------------------------------------
__global__ __launch_bounds__(256) void tree_out(const __half* __restrict__ P,
                                                const float* __restrict__ LL,
                                                float* __restrict__ out) {
  __shared__ __half plds[16 * 520];
  __shared__ f32x4 red[4][64];
  const int tid = threadIdx.x;
  const int lane = tid & 63;
  const int wid = tid >> 6;
  const int r = lane & 15;
  const int g = lane >> 4;
  const int rbase = blockIdx.x * 16;

#pragma unroll
  for (int i = 0; i < 4; ++i) {
    int row = wid * 4 + i;
    LDS16(P + (size_t)(rbase + row) * 512 + lane * 8, plds + row * 520 + lane * 8);
  }

  f16x8 bfr[4];
  const int col = r;
#pragma unroll
  for (int tt = 0; tt < 4; ++tt) {
    int t = wid * 4 + tt;
#pragma unroll
    for (int p = 0; p < 8; ++p) {
      int k0 = t * 32 + g * 8 + p;
      bfr[tt][p] = (col < 10) ? (_Float16)LL[k0 * 10 + col] : (_Float16)0.f;
    }
  }

  __syncthreads();

  const __half* prow = &plds[r * 520];
  f32x4 acc = (f32x4)0.f;
#pragma unroll
  for (int tt = 0; tt < 4; ++tt) {
    const int t = wid * 4 + tt;
    const int L0 = g * 8 + 32 * t;
    float pref = 1.f;
#pragma unroll
    for (int k = 0; k < 6; ++k) {
      int node = L0 >> (9 - k);
      int bit = (L0 >> (8 - k)) & 1;
      float pv = __half2float(prow[(1 << k) - 1 + node]);
      pref *= bit ? pv : (1.f - pv);
    }
    float p6 = __half2float(prow[63 + (L0 >> 3)]);
    float p7a = __half2float(prow[127 + (L0 >> 2)]);
    float p7b = __half2float(prow[128 + (L0 >> 2)]);
    float p80 = __half2float(prow[255 + (L0 >> 1)]);
    float p81 = __half2float(prow[256 + (L0 >> 1)]);
    float p82 = __half2float(prow[257 + (L0 >> 1)]);
    float p83 = __half2float(prow[258 + (L0 >> 1)]);
    float u1 = pref * p6, u0 = pref - u1;
    float v01 = u0 * p7a, v00 = u0 - v01;
    float v11 = u1 * p7b, v10 = u1 - v11;
    float pr1 = v00 * p80, pr0 = v00 - pr1;
    float pr3 = v01 * p81, pr2 = v01 - pr3;
    float pr5 = v10 * p82, pr4 = v10 - pr5;
    float pr7 = v11 * p83, pr6 = v11 - pr7;
    f16x8 af;
    af[0] = (_Float16)pr0; af[1] = (_Float16)pr1;
    af[2] = (_Float16)pr2; af[3] = (_Float16)pr3;
    af[4] = (_Float16)pr4; af[5] = (_Float16)pr5;
    af[6] = (_Float16)pr6; af[7] = (_Float16)pr7;
    acc = __builtin_amdgcn_mfma_f32_16x16x32_f16(af, bfr[tt], acc, 0, 0, 0);
  }

  red[wid][lane] = acc;
  __syncthreads();
  if (wid == 0 && col < 10) {
    f32x4 a0 = red[0][lane], a1 = red[1][lane], a2 = red[2][lane], a3 = red[3][lane];
#pragma unroll
    for (int q = 0; q < 4; ++q)
      out[(size_t)(rbase + g * 4 + q) * 10 + col] = a0[q] + a1[q] + a2[q] + a3[q];
  }
}

// ---------------------------------------------------------------------------
extern "C" void kernel_launch(void* const* d_in, const int* in_sizes, int n_in,
                              void* d_out, int out_size, void* d_ws, size_t ws_size,
                              hipStream_t stream) {
  const float* X = (const float*)d_in[0];
  const float* W = (const float*)d_in[1];
  const float* bv = (const float*)d_in[2];
  const float* LL = (const float*)d_in[3];
  float* out = (float*)d_out;

  __half* P = (__half*)d_ws;                                           // 16 MB
  _Float16* WT = (_Float16*)((char*)d_ws + (size_t)16384 * 512 * 2);   // 1 MB

  prep_w<<<128, 256, 0, stream>>>(W, WT);
  gemm_sig<<<256, 1024, 0, stream>>>(X, WT, bv, P);
  tree_out<<<1024, 256, 0, stream>>>(P, LL, out);
}

// Round 9
// 48.547 us; speedup vs baseline: 1.8565x; 1.0752x over previous
//
#include <hip/hip_runtime.h>
#include <hip/hip_bf16.h>
#include <hip/hip_fp16.h>

typedef unsigned int uint;
typedef unsigned short ushort;
typedef __attribute__((ext_vector_type(4))) float f32x4;
typedef __attribute__((ext_vector_type(8))) _Float16 f16x8;

// async global->LDS (used by tree_out staging only)
#define LDS16(gp, lp)                                                                    \
  __builtin_amdgcn_global_load_lds((const __attribute__((address_space(1))) uint*)(gp),  \
                                   (__attribute__((address_space(3))) uint*)(lp), 16, 0, 0)

// pack two f32 -> one u32 of two f16 (RTZ)
__device__ __forceinline__ uint pk_f16(float a, float b) {
  __fp16 __attribute__((ext_vector_type(2))) r = __builtin_amdgcn_cvt_pkrtz(a, b);
  union { decltype(r) v; uint u; } c;
  c.v = r;
  return c.u;
}

// ---------------------------------------------------------------------------
// Kernel 1: pack W (1024x511 f32, row-major) into MFMA-fragment-ordered f16:
// Bpk[((kt32*32 + ct16)*64 + lane)*8 + j] = W[kt32*32 + (lane>>4)*8 + j]
//                                            [ct16*16 + (lane&15)]  (0-pad c=511)
// One wave B-fragment load becomes 64 lanes x 16B contiguous (1KB burst).
// ---------------------------------------------------------------------------
__global__ __launch_bounds__(256) void prep_b(const float* __restrict__ W,
                                              _Float16* __restrict__ Bpk) {
  const int tg = blockIdx.x * 256 + threadIdx.x;  // 0..65535
  const int lane = tg & 63;
  const int tile = tg >> 6;                       // 0..1023
  const int kt32 = tile >> 5, ct16 = tile & 31;
  const int c = ct16 * 16 + (lane & 15);
  const int k0 = kt32 * 32 + (lane >> 4) * 8;
  f16x8 v;
#pragma unroll
  for (int j = 0; j < 8; ++j)
    v[j] = (c < 511) ? (_Float16)W[(size_t)(k0 + j) * 511 + c] : (_Float16)0.f;
  *(f16x8*)&Bpk[(size_t)tg * 8] = v;
}

// ---------------------------------------------------------------------------
// Kernel 2: P = sigmoid(X @ W + b), f16 [16384][512] (col 511 junk).
// BM=64 x BN=512 (full N): X read exactly once. Grid 256, 1024 threads
// (16 waves 1Mx16N, wave tile 64x32), BK=64, 16 phases.
// B: NO LDS — fragments loaded straight from L2 (Bpk packed, 1KB/wave/load),
//    double-buffered in registers, prefetched one phase ahead; compiler
//    inserts counted vmcnt waits automatically (reg deps).
// A: reg-staged f32 (threads 0..511) -> cvt f16 -> swizzled ds_write_b128,
//    2x8KB LDS dbuf. Raw s_barrier handoff (no full drains).
// ---------------------------------------------------------------------------
__global__ __launch_bounds__(1024, 4) void gemm_sig(const float* __restrict__ X,
                                                    const _Float16* __restrict__ Bpk,
                                                    const float* __restrict__ bvec,
                                                    __half* __restrict__ P) {
  __shared__ _Float16 ldsA[2][64 * 64];  // 2 x 8 KB

  const int tid = threadIdx.x;   // 0..1023
  const int lane = tid & 63;
  const int w = tid >> 6;        // 0..15, wave owns cols [w*32, w*32+32)
  const int l16 = lane & 15;
  const int g = lane >> 4;
  const int rbase = blockIdx.x * 64;

  // A staging (threads 0..511): row = tid>>3, 8 consecutive f32 per thread
  const bool doA = (tid < 512);
  const int arow = tid >> 3;
  const int aseg = tid & 7;
  const float* aSrc = X + (size_t)(rbase + arow) * 1024 + aseg * 8;
  const int awOff = arow * 64 + (aseg ^ (arow & 7)) * 8;  // swizzled 16B slot

  f32x4 acc[4][2];
#pragma unroll
  for (int i = 0; i < 4; ++i)
#pragma unroll
    for (int j = 0; j < 2; ++j) acc[i][j] = (f32x4)0.f;

  f32x4 aR0[2], aR1[2];
  f16x8 bR0[4], bR1[4];

  auto issueA = [&](f32x4* aR, int t) {  // global f32 -> regs (2 x dwordx4)
    if (doA) {
      const float* s = aSrc + t * 64;
      aR[0] = *(const f32x4*)(s);
      aR[1] = *(const f32x4*)(s + 4);
    }
  };

  auto writeA = [&](int buf, const f32x4* aR) {  // cvt + 1 x ds_write_b128
    if (doA) {
      union { uint u[4]; f16x8 v; } c;
      c.u[0] = pk_f16(aR[0][0], aR[0][1]);
      c.u[1] = pk_f16(aR[0][2], aR[0][3]);
      c.u[2] = pk_f16(aR[1][0], aR[1][1]);
      c.u[3] = pk_f16(aR[1][2], aR[1][3]);
      *(f16x8*)&ldsA[buf][awOff] = c.v;
    }
  };

  auto issueB = [&](f16x8* bR, int t) {  // 4 coalesced 1KB wave-loads from L2
#pragma unroll
    for (int kk = 0; kk < 2; ++kk)
#pragma unroll
      for (int ni = 0; ni < 2; ++ni)
        bR[kk * 2 + ni] =
            *(const f16x8*)&Bpk[(size_t)((((2 * t + kk) * 32 + (w << 1) + ni) << 6) + lane) * 8];
  };

  auto compute = [&](int buf, const f16x8* bR) {
#pragma unroll
    for (int kk = 0; kk < 2; ++kk) {
      f16x8 a[4];
#pragma unroll
      for (int mi = 0; mi < 4; ++mi) {
        int r = mi * 16 + l16;
        a[mi] = *(const f16x8*)&ldsA[buf][r * 64 + (((kk * 4 + g) ^ (r & 7)) * 8)];
      }
#pragma unroll
      for (int mi = 0; mi < 4; ++mi)
#pragma unroll
        for (int ni = 0; ni < 2; ++ni)
          acc[mi][ni] = __builtin_amdgcn_mfma_f32_16x16x32_f16(a[mi], bR[kk * 2 + ni],
                                                               acc[mi][ni], 0, 0, 0);
    }
  };

  issueA(aR0, 0);
  issueB(bR0, 0);

#pragma unroll 1
  for (int t = 0; t < 16; t += 2) {
    // ---- phase t (buf 0, regs *0) ----
    writeA(0, aR0);                                      // compiler waits aR0
    asm volatile("s_waitcnt lgkmcnt(0)" ::: "memory");   // my ds_write visible
    __builtin_amdgcn_sched_barrier(0);
    __builtin_amdgcn_s_barrier();                        // A[0] ready for all waves
    __builtin_amdgcn_sched_barrier(0);
    issueA(aR1, t + 1);                                  // prefetch next (t+1<16 always here)
    issueB(bR1, t + 1);
    __builtin_amdgcn_s_setprio(1);
    compute(0, bR0);                                     // compiler waits bR0 (counted)
    __builtin_amdgcn_s_setprio(0);
    __builtin_amdgcn_sched_barrier(0);
    __builtin_amdgcn_s_barrier();                        // all waves done reading A[0]
    // ---- phase t+1 (buf 1, regs *1) ----
    writeA(1, aR1);
    asm volatile("s_waitcnt lgkmcnt(0)" ::: "memory");
    __builtin_amdgcn_sched_barrier(0);
    __builtin_amdgcn_s_barrier();
    __builtin_amdgcn_sched_barrier(0);
    if (t + 2 < 16) {
      issueA(aR0, t + 2);
      issueB(bR0, t + 2);
    }
    __builtin_amdgcn_s_setprio(1);
    compute(1, bR1);
    __builtin_amdgcn_s_setprio(0);
    __builtin_amdgcn_sched_barrier(0);
    __builtin_amdgcn_s_barrier();
  }

  // epilogue: bias + sigmoid, store f16
#pragma unroll
  for (int ni = 0; ni < 2; ++ni) {
    int gc = (w << 5) + ni * 16 + l16;
    float bias = (gc < 511) ? bvec[gc] : 0.f;
#pragma unroll
    for (int mi = 0; mi < 4; ++mi) {
#pragma unroll
      for (int q = 0; q < 4; ++q) {
        int gr = rbase + mi * 16 + g * 4 + q;
        float z = acc[mi][ni][q] + bias;
        float pv = 1.f / (1.f + __expf(-z));
        P[(size_t)gr * 512 + gc] = __float2half(pv);
      }
    }
  }
}

// ---------------------------------------------------------------------------
// Kernel 3: tree propagation + leaf matmul (f16 MFMA).
// 1 block = 16 rows; 4 waves split the 16 t-chunks, partials reduced in LDS.
// ---------------------------------------------------------------------------
__global__ __launch_bounds__(256) void tree_out(const __half* __restrict__ P,
                                                const float* __restrict__ LL,
                                                float* __restrict__ out) {
  __shared__ __half plds[16 * 520];
  __shared__ f32x4 red[4][64];
  const int tid = threadIdx.x;
  const int lane = tid & 63;
  const int wid = tid >> 6;
  const int r = lane & 15;
  const int g = lane >> 4;
  const int rbase = blockIdx.x * 16;

#pragma unroll
  for (int i = 0; i < 4; ++i) {
    int row = wid * 4 + i;
    LDS16(P + (size_t)(rbase + row) * 512 + lane * 8, plds + row * 520 + lane * 8);
  }

  f16x8 bfr[4];
  const int col = r;
#pragma unroll
  for (int tt = 0; tt < 4; ++tt) {
    int t = wid * 4 + tt;
#pragma unroll
    for (int p = 0; p < 8; ++p) {
      int k0 = t * 32 + g * 8 + p;
      bfr[tt][p] = (col < 10) ? (_Float16)LL[k0 * 10 + col] : (_Float16)0.f;
    }
  }

  __syncthreads();

  const __half* prow = &plds[r * 520];
  f32x4 acc = (f32x4)0.f;
#pragma unroll
  for (int tt = 0; tt < 4; ++tt) {
    const int t = wid * 4 + tt;
    const int L0 = g * 8 + 32 * t;
    float pref = 1.f;
#pragma unroll
    for (int k = 0; k < 6; ++k) {
      int node = L0 >> (9 - k);
      int bit = (L0 >> (8 - k)) & 1;
      float pv = __half2float(prow[(1 << k) - 1 + node]);
      pref *= bit ? pv : (1.f - pv);
    }
    float p6 = __half2float(prow[63 + (L0 >> 3)]);
    float p7a = __half2float(prow[127 + (L0 >> 2)]);
    float p7b = __half2float(prow[128 + (L0 >> 2)]);
    float p80 = __half2float(prow[255 + (L0 >> 1)]);
    float p81 = __half2float(prow[256 + (L0 >> 1)]);
    float p82 = __half2float(prow[257 + (L0 >> 1)]);
    float p83 = __half2float(prow[258 + (L0 >> 1)]);
    float u1 = pref * p6, u0 = pref - u1;
    float v01 = u0 * p7a, v00 = u0 - v01;
    float v11 = u1 * p7b, v10 = u1 - v11;
    float pr1 = v00 * p80, pr0 = v00 - pr1;
    float pr3 = v01 * p81, pr2 = v01 - pr3;
    float pr5 = v10 * p82, pr4 = v10 - pr5;
    float pr7 = v11 * p83, pr6 = v11 - pr7;
    f16x8 af;
    af[0] = (_Float16)pr0; af[1] = (_Float16)pr1;
    af[2] = (_Float16)pr2; af[3] = (_Float16)pr3;
    af[4] = (_Float16)pr4; af[5] = (_Float16)pr5;
    af[6] = (_Float16)pr6; af[7] = (_Float16)pr7;
    acc = __builtin_amdgcn_mfma_f32_16x16x32_f16(af, bfr[tt], acc, 0, 0, 0);
  }

  red[wid][lane] = acc;
  __syncthreads();
  if (wid == 0 && col < 10) {
    f32x4 a0 = red[0][lane], a1 = red[1][lane], a2 = red[2][lane], a3 = red[3][lane];
#pragma unroll
    for (int q = 0; q < 4; ++q)
      out[(size_t)(rbase + g * 4 + q) * 10 + col] = a0[q] + a1[q] + a2[q] + a3[q];
  }
}

// ---------------------------------------------------------------------------
extern "C" void kernel_launch(void* const* d_in, const int* in_sizes, int n_in,
                              void* d_out, int out_size, void* d_ws, size_t ws_size,
                              hipStream_t stream) {
  const float* X = (const float*)d_in[0];
  const float* W = (const float*)d_in[1];
  const float* bv = (const float*)d_in[2];
  const float* LL = (const float*)d_in[3];
  float* out = (float*)d_out;

  __half* P = (__half*)d_ws;                                          // 16 MB
  _Float16* Bpk = (_Float16*)((char*)d_ws + (size_t)16384 * 512 * 2); // 1 MB

  prep_b<<<256, 256, 0, stream>>>(W, Bpk);
  gemm_sig<<<256, 1024, 0, stream>>>(X, Bpk, bv, P);
  tree_out<<<1024, 256, 0, stream>>>(P, LL, out);
}